// Round 16
// baseline (455.860 us; speedup 1.0000x reference)
//
#include <hip/hip_runtime.h>
#include <math.h>

typedef unsigned short u16;
typedef unsigned int   u32;
using bf16x8 = __attribute__((ext_vector_type(8))) short;
using f32x4  = __attribute__((ext_vector_type(4))) float;
using f32x16 = __attribute__((ext_vector_type(16))) float;

static constexpr int Bb = 2, Tt = 2048, Cc = 1024, Hh = 16, Dd = 64;
static constexpr int QS = 3072;   // fused qkv row stride (u16 elements)
static constexpr float QSCALE = 0.125f * 1.44269504089f;  // folded into Q at QKV epilogue

__device__ __forceinline__ u16 f2bf(float f){
  u32 u = __builtin_bit_cast(u32, f);
  u += 0x7fffu + ((u >> 16) & 1u);
  return (u16)(u >> 16);
}
__device__ __forceinline__ float bf2f(u16 v){
  u32 u = (u32)v << 16;
  return __builtin_bit_cast(float, u);
}

__device__ __forceinline__ void gl2lds16(const void* g, void* l){
  __builtin_amdgcn_global_load_lds((const __attribute__((address_space(1))) void*)g,
                                   (__attribute__((address_space(3))) void*)l, 16, 0, 0);
}

template<int N> __device__ __forceinline__ void waitvm(){
  if constexpr (N == 0) asm volatile("s_waitcnt vmcnt(0)" ::: "memory");
  else if constexpr (N == 4) asm volatile("s_waitcnt vmcnt(4)" ::: "memory");
  else if constexpr (N == 6) asm volatile("s_waitcnt vmcnt(6)" ::: "memory");
  else if constexpr (N == 8) asm volatile("s_waitcnt vmcnt(8)" ::: "memory");
}

__device__ __forceinline__ void barrier_pin(){
  __builtin_amdgcn_s_barrier();
  __builtin_amdgcn_sched_barrier(0);
}

__device__ __forceinline__ f32x4 mfma16(bf16x8 a, bf16x8 b, f32x4 c){
  return __builtin_amdgcn_mfma_f32_16x16x32_bf16(a, b, c, 0, 0, 0);
}
__device__ __forceinline__ f32x16 mfma32(bf16x8 a, bf16x8 b, f32x16 c){
  return __builtin_amdgcn_mfma_f32_32x32x16_bf16(a, b, c, 0, 0, 0);
}

__device__ __forceinline__ float exp2f_fast(float x){
#if __has_builtin(__builtin_amdgcn_exp2f)
  return __builtin_amdgcn_exp2f(x);
#else
  return __expf(x * 0.69314718056f);
#endif
}

__device__ __forceinline__ float gelu_f(float x){
  return 0.5f * x * (1.0f + erff(x * 0.70710678118654752f));
}

__device__ __forceinline__ void plane_swap(u32& a, u32& b){
  asm("v_permlane32_swap_b32 %0, %1" : "+v"(a), "+v"(b));
}
__device__ __forceinline__ u32 cvtpk_bf16(float lo, float hi){
  u32 r;
  asm("v_cvt_pk_bf16_f32 %0, %1, %2" : "=v"(r) : "v"(lo), "v"(hi));
  return r;
}

__device__ __forceinline__ bf16x8 ldlds(const u16* p){ return *(const bf16x8*)p; }

// ---------------- LayerNorm: fp32 row -> bf16 row ----------------
__global__ __launch_bounds__(256) void ln_kernel(const float* __restrict__ x,
    const float* __restrict__ g, const float* __restrict__ b, u16* __restrict__ out)
{
  int row = blockIdx.x;
  int tid = threadIdx.x;
  const float4* xr = (const float4*)(x + (size_t)row * Cc);
  float4 v = xr[tid];
  float s  = v.x + v.y + v.z + v.w;
  float s2 = v.x*v.x + v.y*v.y + v.z*v.z + v.w*v.w;
  #pragma unroll
  for (int off = 1; off < 64; off <<= 1){ s += __shfl_xor(s, off); s2 += __shfl_xor(s2, off); }
  __shared__ float red[8];
  int wid = tid >> 6;
  if ((tid & 63) == 0){ red[wid] = s; red[4 + wid] = s2; }
  __syncthreads();
  s  = red[0] + red[1] + red[2] + red[3];
  s2 = red[4] + red[5] + red[6] + red[7];
  float mu   = s * (1.0f / Cc);
  float var  = s2 * (1.0f / Cc) - mu * mu;
  float rstd = rsqrtf(var + 1e-5f);
  const float4 gg = ((const float4*)g)[tid];
  const float4 bb = ((const float4*)b)[tid];
  ushort4 o;
  o.x = f2bf((v.x - mu) * rstd * gg.x + bb.x);
  o.y = f2bf((v.y - mu) * rstd * gg.y + bb.y);
  o.z = f2bf((v.z - mu) * rstd * gg.z + bb.z);
  o.w = f2bf((v.w - mu) * rstd * gg.w + bb.w);
  *(ushort4*)(out + (size_t)row * Cc + tid * 4) = o;
}

// ---------------- transpose + cast: W[K][N] fp32 -> WT[N][K] bf16 ----------------
__global__ __launch_bounds__(256) void transpose_cast_kernel(const float* __restrict__ in,
    u16* __restrict__ out, int R, int Ccols)
{
  __shared__ float tile[32][33];
  int tx = threadIdx.x, ty = threadIdx.y;
  int c0 = blockIdx.x * 32, r0 = blockIdx.y * 32;
  #pragma unroll
  for (int j = 0; j < 4; j++) tile[ty + j*8][tx] = in[(size_t)(r0 + ty + j*8) * Ccols + c0 + tx];
  __syncthreads();
  #pragma unroll
  for (int j = 0; j < 4; j++) out[(size_t)(c0 + ty + j*8) * R + r0 + tx] = f2bf(tile[tx][ty + j*8]);
}

// ---------------- 4x fused 1024x1024 transpose+cast ----------------
__global__ __launch_bounds__(256) void transpose4_kernel(
    const float* __restrict__ s0, const float* __restrict__ s1,
    const float* __restrict__ s2, const float* __restrict__ s3,
    u16* __restrict__ d0, u16* __restrict__ d1, u16* __restrict__ d2, u16* __restrict__ d3)
{
  __shared__ float tile[32][33];
  int z = blockIdx.z;
  const float* in = (z == 0) ? s0 : (z == 1) ? s1 : (z == 2) ? s2 : s3;
  u16* out        = (z == 0) ? d0 : (z == 1) ? d1 : (z == 2) ? d2 : d3;
  int tx = threadIdx.x, ty = threadIdx.y;
  int c0 = blockIdx.x * 32, r0 = blockIdx.y * 32;
  #pragma unroll
  for (int j = 0; j < 4; j++) tile[ty + j*8][tx] = in[(size_t)(r0 + ty + j*8) * 1024 + c0 + tx];
  __syncthreads();
  #pragma unroll
  for (int j = 0; j < 4; j++) out[(size_t)(c0 + ty + j*8) * 1024 + r0 + tx] = f2bf(tile[tx][ty + j*8]);
}

// ---------------- pack 3 bias vectors into one [3072] ----------------
__global__ __launch_bounds__(256) void pack3_kernel(const float* __restrict__ a,
    const float* __restrict__ b, const float* __restrict__ c, float* __restrict__ o)
{
  int i = blockIdx.x * 256 + threadIdx.x;
  float v = (i < 1024) ? a[i] : (i < 2048 ? b[i - 1024] : c[i - 2048]);
  o[i] = v;
}

// ---------------- v slice of qkv (stride QS) -> vt (B,H,D,T) bf16 ----------------
__global__ __launch_bounds__(256) void transpose_v_kernel(const u16* __restrict__ v, u16* __restrict__ vt)
{
  __shared__ u16 tile[32][33];
  int tx = threadIdx.x, ty = threadIdx.y;
  int bh = blockIdx.z; int b = bh >> 4, h = bh & 15;
  int t0 = blockIdx.x * 32, d0 = blockIdx.y * 32;
  const u16* src = v + (size_t)b * Tt * QS + h * Dd;
  #pragma unroll
  for (int j = 0; j < 4; j++) tile[ty + j*8][tx] = src[(size_t)(t0 + ty + j*8) * QS + d0 + tx];
  __syncthreads();
  u16* dst = vt + (size_t)bh * Dd * Tt;
  #pragma unroll
  for (int j = 0; j < 4; j++) dst[(size_t)(d0 + ty + j*8) * Tt + t0 + tx] = tile[tx][ty + j*8];
}

// ======== BK=32 high-occupancy GEMM (T4+T2+T1), 128x128, 5 blocks/CU ========
// 256 threads = 4 waves (2M x 2N, each 64x64). LDS 32KB dbuf -> 5 resident blocks
// (20 waves/CU): 5 independent counted-vmcnt streams hide the per-tile latency.
// Swizzle: proven-conflict-free 32-col formula w = p ^ ((row>>1)&3) (gemm8p, 0 conflicts).
// EPI 2: bf16 (+bias, gelu); 3: bf16 (+bias, q-cols * QSCALE)
template<int EPI>
__global__ __launch_bounds__(256, 5) void gemm32_kernel(
    const u16* __restrict__ A, const u16* __restrict__ BT,
    const float* __restrict__ bias, void* __restrict__ out,
    int K, int ldA, int ldOut)
{
  __shared__ alignas(16) u16 As[2][128 * 32];
  __shared__ alignas(16) u16 Bs[2][128 * 32];

  const int tid  = threadIdx.x;
  const int lane = tid & 63, wid = tid >> 6;
  const int l15  = lane & 15, lg = lane >> 4;

  // bijective XCD-chunked grid swizzle (all launches have nwg % 8 == 0)
  const int gx  = gridDim.x;
  const int lin = blockIdx.x + gx * blockIdx.y;
  const int nwg = gx * gridDim.y;
  const int wl  = (lin & 7) * (nwg >> 3) + (lin >> 3);
  const int rowBase = (wl % gx) * 128, colBase = (wl / gx) * 128;

  const int wr = wid >> 1, wc = wid & 1;

  f32x4 acc[4][4] = {};

  // staging: granule g = tid + 256*j (j=0,1); row = g>>2, p = g&3, w = p ^ ((row>>1)&3)
  const int g0 = tid, g1 = tid + 256;
  const int r0 = g0 >> 2, w0 = (g0 & 3) ^ ((r0 >> 1) & 3);
  const int r1 = g1 >> 2, w1 = (g1 & 3) ^ ((r1 >> 1) & 3);
  const u16* pA0 = A  + (size_t)(rowBase + r0) * ldA + w0 * 8;
  const u16* pA1 = A  + (size_t)(rowBase + r1) * ldA + w1 * 8;
  const u16* pB0 = BT + (size_t)(colBase + r0) * K   + w0 * 8;
  const u16* pB1 = BT + (size_t)(colBase + r1) * K   + w1 * 8;
  const u32 d0 = (u32)g0 * 8, d1 = (u32)g1 * 8;

  // LDS read offsets (u16 units): row r, granule (lg ^ ((r>>1)&3))
  u32 oa[4], ob[4];
  #pragma unroll
  for (int mi = 0; mi < 4; mi++){
    int r = wr * 64 + mi * 16 + l15;
    oa[mi] = (u32)(r * 32 + ((lg ^ ((r >> 1) & 3)) << 3));
  }
  #pragma unroll
  for (int ni = 0; ni < 4; ni++){
    int r = wc * 64 + ni * 16 + l15;
    ob[ni] = (u32)(r * 32 + ((lg ^ ((r >> 1) & 3)) << 3));
  }

  // prologue: stage tile 0
  gl2lds16(pA0, &As[0][d0]); gl2lds16(pA1, &As[0][d1]);
  gl2lds16(pB0, &Bs[0][d0]); gl2lds16(pB1, &Bs[0][d1]);
  pA0 += 32; pA1 += 32; pB0 += 32; pB1 += 32;

  const int nt = K >> 5;
  #pragma unroll 2
  for (int t = 0; t < nt - 1; ++t){
    const int cur = t & 1, nxt = cur ^ 1;
    gl2lds16(pA0, &As[nxt][d0]); gl2lds16(pA1, &As[nxt][d1]);
    gl2lds16(pB0, &Bs[nxt][d0]); gl2lds16(pB1, &Bs[nxt][d1]);
    pA0 += 32; pA1 += 32; pB0 += 32; pB1 += 32;
    waitvm<4>();
    __builtin_amdgcn_s_barrier();
    __builtin_amdgcn_sched_barrier(0);

    bf16x8 afr[4], bfr[4];
    #pragma unroll
    for (int mi = 0; mi < 4; mi++) afr[mi] = ldlds(&As[cur][oa[mi]]);
    #pragma unroll
    for (int ni = 0; ni < 4; ni++) bfr[ni] = ldlds(&Bs[cur][ob[ni]]);
    __builtin_amdgcn_s_setprio(1);
    #pragma unroll
    for (int mi = 0; mi < 4; mi++)
      #pragma unroll
      for (int ni = 0; ni < 4; ni++)
        acc[mi][ni] = mfma16(afr[mi], bfr[ni], acc[mi][ni]);
    __builtin_amdgcn_s_setprio(0);

    __builtin_amdgcn_sched_barrier(0);
    __builtin_amdgcn_s_barrier();
  }
  { // epilogue tile
    const int cur = (nt - 1) & 1;
    waitvm<0>();
    __builtin_amdgcn_s_barrier();
    bf16x8 afr[4], bfr[4];
    #pragma unroll
    for (int mi = 0; mi < 4; mi++) afr[mi] = ldlds(&As[cur][oa[mi]]);
    #pragma unroll
    for (int ni = 0; ni < 4; ni++) bfr[ni] = ldlds(&Bs[cur][ob[ni]]);
    #pragma unroll
    for (int mi = 0; mi < 4; mi++)
      #pragma unroll
      for (int ni = 0; ni < 4; ni++)
        acc[mi][ni] = mfma16(afr[mi], bfr[ni], acc[mi][ni]);
  }

  #pragma unroll
  for (int mi = 0; mi < 4; mi++){
    #pragma unroll
    for (int ni = 0; ni < 4; ni++){
      int row = rowBase + wr * 64 + mi * 16 + lg * 4;
      int col = colBase + wc * 64 + ni * 16 + l15;
      float bc = bias[col];
      #pragma unroll
      for (int r = 0; r < 4; r++){
        float val = acc[mi][ni][r] + bc;
        size_t idx = (size_t)(row + r) * ldOut + col;
        if constexpr (EPI == 2) ((u16*)out)[idx] = f2bf(gelu_f(val));
        else                    ((u16*)out)[idx] = f2bf(col < 1024 ? val * QSCALE : val);
      }
    }
  }
}

// ======== small-tile counted-vmcnt GEMM (T4+T2+T1), 64x64 BK=64 (Wo / W2) ========
// EPI 1: f32 out (+bias+residual)
template<int BM, int BN, int WPEU, int EPI>
__global__ __launch_bounds__(256, WPEU) void gemmc_kernel(
    const u16* __restrict__ A, const u16* __restrict__ BT,
    const float* __restrict__ bias, const float* __restrict__ resid,
    void* __restrict__ out, int K, int ldA, int ldOut)
{
  constexpr int MF = BM / 2 / 16;
  constexpr int NF = BN / 2 / 16;
  constexpr int AG = BM / 32;
  constexpr int BG = BN / 32;
  constexpr int NLOADS = AG + BG;

  __shared__ alignas(16) u16 As[2][BM * 64];
  __shared__ alignas(16) u16 Bs[2][BN * 64];

  const int tid  = threadIdx.x;
  const int lane = tid & 63, wid = tid >> 6;
  const int l15  = lane & 15, lg = lane >> 4;

  const int gx  = gridDim.x;
  const int lin = blockIdx.x + gx * blockIdx.y;
  const int nwg = gx * gridDim.y;
  const int wl  = (lin & 7) * (nwg >> 3) + (lin >> 3);
  const int rowBase = (wl % gx) * BM, colBase = (wl / gx) * BN;

  const int wr = wid >> 1, wc = wid & 1;

  f32x4 acc[MF][NF] = {};

  const u16* pA[AG];
  const u16* pB[BG];
  u32 dA[AG], dB[BG];
  #pragma unroll
  for (int j = 0; j < AG; j++){
    int g = tid + 256 * j;
    int r = g >> 3, w = (g & 7) ^ (r & 7);
    pA[j] = A + (size_t)(rowBase + r) * ldA + w * 8;
    dA[j] = (u32)g * 8;
  }
  #pragma unroll
  for (int j = 0; j < BG; j++){
    int g = tid + 256 * j;
    int r = g >> 3, w = (g & 7) ^ (r & 7);
    pB[j] = BT + (size_t)(colBase + r) * K + w * 8;
    dB[j] = (u32)g * 8;
  }

  u32 oa[MF][2], ob[NF][2];
  #pragma unroll
  for (int mi = 0; mi < MF; mi++){
    int r = wr * (BM / 2) + mi * 16 + l15;
    oa[mi][0] = (u32)(r * 64 + ((lg       ^ (r & 7)) << 3));
    oa[mi][1] = (u32)(r * 64 + (((4 + lg) ^ (r & 7)) << 3));
  }
  #pragma unroll
  for (int ni = 0; ni < NF; ni++){
    int r = wc * (BN / 2) + ni * 16 + l15;
    ob[ni][0] = (u32)(r * 64 + ((lg       ^ (r & 7)) << 3));
    ob[ni][1] = (u32)(r * 64 + (((4 + lg) ^ (r & 7)) << 3));
  }

  #pragma unroll
  for (int j = 0; j < AG; j++){ gl2lds16(pA[j], &As[0][dA[j]]); pA[j] += 64; }
  #pragma unroll
  for (int j = 0; j < BG; j++){ gl2lds16(pB[j], &Bs[0][dB[j]]); pB[j] += 64; }

  const int nt = K >> 6;
  #pragma unroll 2
  for (int t = 0; t < nt - 1; ++t){
    const int cur = t & 1, nxt = cur ^ 1;
    #pragma unroll
    for (int j = 0; j < AG; j++){ gl2lds16(pA[j], &As[nxt][dA[j]]); pA[j] += 64; }
    #pragma unroll
    for (int j = 0; j < BG; j++){ gl2lds16(pB[j], &Bs[nxt][dB[j]]); pB[j] += 64; }
    waitvm<NLOADS>();
    __builtin_amdgcn_s_barrier();
    __builtin_amdgcn_sched_barrier(0);

    bf16x8 afr[MF][2], bfr[NF][2];
    #pragma unroll
    for (int mi = 0; mi < MF; mi++){
      afr[mi][0] = ldlds(&As[cur][oa[mi][0]]);
      afr[mi][1] = ldlds(&As[cur][oa[mi][1]]);
    }
    #pragma unroll
    for (int ni = 0; ni < NF; ni++){
      bfr[ni][0] = ldlds(&Bs[cur][ob[ni][0]]);
      bfr[ni][1] = ldlds(&Bs[cur][ob[ni][1]]);
    }
    __builtin_amdgcn_s_setprio(1);
    #pragma unroll
    for (int mi = 0; mi < MF; mi++)
      #pragma unroll
      for (int ni = 0; ni < NF; ni++){
        acc[mi][ni] = mfma16(afr[mi][0], bfr[ni][0], acc[mi][ni]);
        acc[mi][ni] = mfma16(afr[mi][1], bfr[ni][1], acc[mi][ni]);
      }
    __builtin_amdgcn_s_setprio(0);

    __builtin_amdgcn_sched_barrier(0);
    __builtin_amdgcn_s_barrier();
  }
  {
    const int cur = (nt - 1) & 1;
    waitvm<0>();
    __builtin_amdgcn_s_barrier();
    bf16x8 afr[MF][2], bfr[NF][2];
    #pragma unroll
    for (int mi = 0; mi < MF; mi++){
      afr[mi][0] = ldlds(&As[cur][oa[mi][0]]);
      afr[mi][1] = ldlds(&As[cur][oa[mi][1]]);
    }
    #pragma unroll
    for (int ni = 0; ni < NF; ni++){
      bfr[ni][0] = ldlds(&Bs[cur][ob[ni][0]]);
      bfr[ni][1] = ldlds(&Bs[cur][ob[ni][1]]);
    }
    #pragma unroll
    for (int mi = 0; mi < MF; mi++)
      #pragma unroll
      for (int ni = 0; ni < NF; ni++){
        acc[mi][ni] = mfma16(afr[mi][0], bfr[ni][0], acc[mi][ni]);
        acc[mi][ni] = mfma16(afr[mi][1], bfr[ni][1], acc[mi][ni]);
      }
  }

  #pragma unroll
  for (int mi = 0; mi < MF; mi++){
    #pragma unroll
    for (int ni = 0; ni < NF; ni++){
      int row = rowBase + wr * (BM / 2) + mi * 16 + lg * 4;
      int col = colBase + wc * (BN / 2) + ni * 16 + l15;
      float bc = bias[col];
      #pragma unroll
      for (int r = 0; r < 4; r++){
        float val = acc[mi][ni][r] + bc;
        size_t idx = (size_t)(row + r) * ldOut + col;
        if constexpr (EPI == 1) ((float*)out)[idx] = val + resid[idx];
        else                    ((u16*)out)[idx]   = f2bf(val);
      }
    }
  }
}

// ---------------- Flash attention, swapped 32x32, KV-split x2 ----------------
__global__ __launch_bounds__(256, 4) void attn_kernel(const u16* __restrict__ q, const u16* __restrict__ k,
    const u16* __restrict__ vt, u16* __restrict__ opart, float* __restrict__ ml)
{
  __shared__ alignas(16) u16 Ks[2][64 * 64];
  __shared__ alignas(16) u16 Vs[2][64 * 64];
  int tid  = threadIdx.x;
  int lane = tid & 63, wid = tid >> 6;
  int l31  = lane & 31, hi = lane >> 5;

  int lin = blockIdx.x + 16 * blockIdx.y;
  int wl  = (lin & 7) * 64 + (lin >> 3);
  int qt  = wl & 15, bh = wl >> 4;
  int b = bh >> 4, h = bh & 15;
  int split = blockIdx.z;
  int kt0 = split * (Tt / 2);

  int qglob = qt * 128 + wid * 32 + l31;

  const u16* qp = q + ((size_t)b * Tt + qglob) * QS + h * Dd + hi * 8;
  bf16x8 qf[4];
  #pragma unroll
  for (int s = 0; s < 4; s++) qf[s] = *(const bf16x8*)(qp + s * 16);

  const u16* kbase = k  + (size_t)b * Tt * QS + h * Dd;
  const u16* vbase = vt + (size_t)bh * Dd * Tt;

  f32x16 yacc[2] = {};
  float m2 = -1e30f, lsum = 0.f;

  int g0 = tid, g1 = tid + 256;
  int r0 = g0 >> 3, cb0 = (g0 & 7) ^ (r0 & 7);
  int r1 = g1 >> 3, cb1 = (g1 & 7) ^ (r1 & 7);

  auto stageKV = [&](int buf, int kt){
    gl2lds16(kbase + (size_t)(kt + r0) * QS + cb0 * 8, (u16*)Ks[buf] + wid * 512);
    gl2lds16(kbase + (size_t)(kt + r1) * QS + cb1 * 8, (u16*)Ks[buf] + 2048 + wid * 512);
    gl2lds16(vbase + (size_t)r0 * Tt + kt + cb0 * 8,   (u16*)Vs[buf] + wid * 512);
    gl2lds16(vbase + (size_t)r1 * Tt + kt + cb1 * 8,   (u16*)Vs[buf] + 2048 + wid * 512);
  };

  stageKV(0, kt0);
  int cur = 0;
  for (int kt = kt0; kt < kt0 + Tt / 2; kt += 64) {
    if (kt + 64 < kt0 + Tt / 2) { stageKV(cur ^ 1, kt + 64); waitvm<4>(); }
    else                        { waitvm<0>(); }
    barrier_pin();

    const u16* Ksb = (const u16*)Ks[cur];
    const u16* Vsb = (const u16*)Vs[cur];
    int rx = l31 & 7;

    f32x16 st[2] = {};
    __builtin_amdgcn_s_setprio(1);
    #pragma unroll
    for (int nb = 0; nb < 2; nb++){
      const u16* krow = Ksb + (nb * 32 + l31) * 64;
      #pragma unroll
      for (int s = 0; s < 4; s++){
        bf16x8 kf = *(const bf16x8*)(krow + (((s * 2 + hi) ^ rx) << 3));
        st[nb] = mfma32(kf, qf[s], st[nb]);
      }
    }
    __builtin_amdgcn_s_setprio(0);

    float tm[16];
    #pragma unroll
    for (int i = 0; i < 16; i++) tm[i] = fmaxf(st[0][i], st[1][i]);
    #pragma unroll
    for (int w = 8; w; w >>= 1)
      #pragma unroll
      for (int i = 0; i < w; i++) tm[i] = fmaxf(tm[i], tm[i + w]);
    u32 ma = __builtin_bit_cast(u32, tm[0]), mb = ma;
    plane_swap(ma, mb);
    float mx = fmaxf(__builtin_bit_cast(float, ma), __builtin_bit_cast(float, mb));

    float mnew = fmaxf(m2, mx);
    float alpha = exp2f_fast(m2 - mnew);
    m2 = mnew;

    #pragma unroll
    for (int nb = 0; nb < 2; nb++)
      #pragma unroll
      for (int i = 0; i < 16; i++)
        st[nb][i] = exp2f_fast(st[nb][i] - m2);

    float ts[16];
    #pragma unroll
    for (int i = 0; i < 16; i++) ts[i] = st[0][i] + st[1][i];
    #pragma unroll
    for (int w = 8; w; w >>= 1)
      #pragma unroll
      for (int i = 0; i < w; i++) ts[i] += ts[i + w];
    u32 sa = __builtin_bit_cast(u32, ts[0]), sb = sa;
    plane_swap(sa, sb);
    lsum = lsum * alpha + __builtin_bit_cast(float, sa) + __builtin_bit_cast(float, sb);

    #pragma unroll
    for (int nd = 0; nd < 2; nd++)
      #pragma unroll
      for (int i = 0; i < 16; i++) yacc[nd][i] *= alpha;

    bf16x8 pb[4];
    #pragma unroll
    for (int nb = 0; nb < 2; nb++){
      u32 c[8];
      #pragma unroll
      for (int i = 0; i < 8; i++) c[i] = cvtpk_bf16(st[nb][2 * i], st[nb][2 * i + 1]);
      plane_swap(c[0], c[2]); plane_swap(c[1], c[3]);
      plane_swap(c[4], c[6]); plane_swap(c[5], c[7]);
      u32 f0[4] = {c[0], c[1], c[2], c[3]};
      u32 f1[4] = {c[4], c[5], c[6], c[7]};
      pb[nb * 2 + 0] = *(bf16x8*)f0;
      pb[nb * 2 + 1] = *(bf16x8*)f1;
    }

    __builtin_amdgcn_s_setprio(1);
    #pragma unroll
    for (int nd = 0; nd < 2; nd++){
      const u16* vrow = Vsb + (nd * 32 + l31) * 64;
      #pragma unroll
      for (int ks = 0; ks < 4; ks++){
        bf16x8 vf = *(const bf16x8*)(vrow + (((ks * 2 + hi) ^ rx) << 3));
        yacc[nd] = mfma32(vf, pb[ks], yacc[nd]);
      }
    }
    __builtin_amdgcn_s_setprio(0);

    __builtin_amdgcn_sched_barrier(0);
    barrier_pin();
    cur ^= 1;
  }

  float inv = 1.0f / lsum;
  u16* op = opart + ((size_t)split * (Bb * Tt) + (size_t)b * Tt + qglob) * Cc + h * Dd;
  #pragma unroll
  for (int nd = 0; nd < 2; nd++){
    #pragma unroll
    for (int g = 0; g < 4; g++){
      ushort4 o;
      o.x = f2bf(yacc[nd][g * 4 + 0] * inv);
      o.y = f2bf(yacc[nd][g * 4 + 1] * inv);
      o.z = f2bf(yacc[nd][g * 4 + 2] * inv);
      o.w = f2bf(yacc[nd][g * 4 + 3] * inv);
      *(ushort4*)(op + nd * 32 + g * 8 + hi * 4) = o;
    }
  }
  if (hi == 0){
    float* mlp = ml + (((size_t)split * (Bb * Tt) + (size_t)b * Tt + qglob) * Hh + h) * 2;
    mlp[0] = m2; mlp[1] = lsum;
  }
}

// ---------------- combine 2 KV-splits (convex combination of normalized partials) ----
__global__ __launch_bounds__(256) void combine_kernel(const u16* __restrict__ opart,
    const float* __restrict__ ml, u16* __restrict__ y)
{
  int row = blockIdx.x;
  int d0  = threadIdx.x * 4;
  int h   = d0 >> 6;
  const float* p0 = ml + ((size_t)row * Hh + h) * 2;
  const float* p1 = ml + (((size_t)(Bb * Tt) + row) * Hh + h) * 2;
  float m0 = p0[0], l0 = p0[1], m1 = p1[0], l1 = p1[1];
  float M  = fmaxf(m0, m1);
  float u0 = l0 * exp2f_fast(m0 - M), u1 = l1 * exp2f_fast(m1 - M);
  float inv = 1.0f / (u0 + u1);
  float w0 = u0 * inv, w1 = u1 * inv;
  ushort4 a = *(const ushort4*)(opart + (size_t)row * Cc + d0);
  ushort4 c = *(const ushort4*)(opart + ((size_t)(Bb * Tt) + row) * Cc + d0);
  ushort4 o;
  o.x = f2bf(bf2f(a.x) * w0 + bf2f(c.x) * w1);
  o.y = f2bf(bf2f(a.y) * w0 + bf2f(c.y) * w1);
  o.z = f2bf(bf2f(a.z) * w0 + bf2f(c.z) * w1);
  o.w = f2bf(bf2f(a.w) * w0 + bf2f(c.w) * w1);
  *(ushort4*)(y + (size_t)row * Cc + d0) = o;
}

extern "C" void kernel_launch(void* const* d_in, const int* in_sizes, int n_in,
                              void* d_out, int out_size, void* d_ws, size_t ws_size,
                              hipStream_t stream)
{
  (void)in_sizes; (void)n_in; (void)out_size; (void)ws_size;
  const float* x    = (const float*)d_in[0];
  const float* Wq   = (const float*)d_in[1];
  const float* bq   = (const float*)d_in[2];
  const float* Wk   = (const float*)d_in[3];
  const float* bk   = (const float*)d_in[4];
  const float* Wv   = (const float*)d_in[5];
  const float* bv   = (const float*)d_in[6];
  const float* Wo   = (const float*)d_in[7];
  const float* bo   = (const float*)d_in[8];
  const float* ln1g = (const float*)d_in[9];
  const float* ln1b = (const float*)d_in[10];
  const float* ln2g = (const float*)d_in[11];
  const float* ln2b = (const float*)d_in[12];
  const float* W1   = (const float*)d_in[13];
  const float* b1   = (const float*)d_in[14];
  const float* W2   = (const float*)d_in[15];
  const float* b2   = (const float*)d_in[16];

  char* ws = (char*)d_ws;
  const size_t MB = 1024 * 1024;
  u16*   wqkvt = (u16*)(ws + 0 * MB);      // 6 MB  (Wq^T | Wk^T | Wv^T rows)
  u16*   wot   = (u16*)(ws + 6 * MB);      // 2 MB
  u16*   w1t   = (u16*)(ws + 8 * MB);      // 8 MB
  u16*   w2t   = (u16*)(ws + 16 * MB);     // 8 MB
  float* bqkv  = (float*)(ws + 24 * MB);   // 12 KB
  u16*   hbuf  = (u16*)(ws + 25 * MB);     // 8 MB  (h2 overlays after QKV gemm)
  u16*   qkv   = (u16*)(ws + 33 * MB);     // 24 MB (mb overlays 33..65 after attn)
  u16*   vtb   = (u16*)(ws + 57 * MB);     // 8 MB
  u16*   yb    = (u16*)(ws + 65 * MB);     // 8 MB
  u16*   opart = (u16*)(ws + 73 * MB);     // 16 MB (2 splits x 8 MB)
  float* x2    = (float*)(ws + 73 * MB);   // 16 MB (written by Wo gemm, after combine)
  float* mlb   = (float*)(ws + 89 * MB);   // 1 MB
  u16*   h2    = hbuf;
  u16*   mb    = qkv;

  dim3 tb(32, 8);
  transpose4_kernel<<<dim3(32, 32, 4), tb, 0, stream>>>(Wq, Wk, Wv, Wo,
      wqkvt, wqkvt + 1024 * 1024, wqkvt + 2048 * 1024, wot);
  transpose_cast_kernel<<<dim3(128, 32), tb, 0, stream>>>(W1, w1t, 1024, 4096);
  transpose_cast_kernel<<<dim3(32, 128), tb, 0, stream>>>(W2, w2t, 4096, 1024);
  pack3_kernel<<<12, 256, 0, stream>>>(bq, bk, bv, bqkv);

  ln_kernel<<<4096, 256, 0, stream>>>(x, ln1g, ln1b, hbuf);

  // fused QKV: 128x128 BK=32, 768 blocks, 5 blocks/CU (EPI 3: q cols pre-scaled)
  gemm32_kernel<3><<<dim3(32, 24), 256, 0, stream>>>(hbuf, wqkvt, bqkv, qkv, 1024, 1024, 3072);

  transpose_v_kernel<<<dim3(64, 2, 32), tb, 0, stream>>>(qkv + 2048, vtb);

  // KV-split x2 attention + combine
  attn_kernel<<<dim3(16, 32, 2), 256, 0, stream>>>(qkv, qkv + 1024, vtb, opart, mlb);
  combine_kernel<<<4096, 256, 0, stream>>>(opart, mlb, yb);

  // Wo: 64x64 tiles, 1024 blocks, 4 blocks/CU
  gemmc_kernel<64, 64, 4, 1><<<dim3(64, 16), 256, 0, stream>>>(yb, wot, bo, x, x2, 1024, 1024, 1024);

  ln_kernel<<<4096, 256, 0, stream>>>(x2, ln2g, ln2b, h2);

  // W1: 128x128 BK=32, 1024 blocks, 5 blocks/CU (gelu)
  gemm32_kernel<2><<<dim3(32, 32), 256, 0, stream>>>(h2, w1t, b1, mb, 1024, 1024, 4096);

  // W2: 64x64 tiles BK=64, 1024 blocks, 4 blocks/CU (R13 proven)
  gemmc_kernel<64, 64, 4, 1><<<dim3(64, 16), 256, 0, stream>>>(mb, w2t, b2, x2, (float*)d_out, 4096, 4096, 1024);
}

// Round 17
// 246.602 us; speedup vs baseline: 1.8486x; 1.8486x over previous
//
#include <hip/hip_runtime.h>
#include <math.h>

typedef unsigned short u16;
typedef unsigned int   u32;
using bf16x8 = __attribute__((ext_vector_type(8))) short;
using f32x4  = __attribute__((ext_vector_type(4))) float;
using f32x16 = __attribute__((ext_vector_type(16))) float;

static constexpr int Bb = 2, Tt = 2048, Cc = 1024, Hh = 16, Dd = 64;
static constexpr int QS = 3072;   // fused qkv row stride (u16 elements)
static constexpr float QSCALE = 0.125f * 1.44269504089f;  // folded into Q at QKV epilogue

__device__ __forceinline__ u16 f2bf(float f){
  u32 u = __builtin_bit_cast(u32, f);
  u += 0x7fffu + ((u >> 16) & 1u);
  return (u16)(u >> 16);
}
__device__ __forceinline__ float bf2f(u16 v){
  u32 u = (u32)v << 16;
  return __builtin_bit_cast(float, u);
}

__device__ __forceinline__ void gl2lds16(const void* g, void* l){
  __builtin_amdgcn_global_load_lds((const __attribute__((address_space(1))) void*)g,
                                   (__attribute__((address_space(3))) void*)l, 16, 0, 0);
}

template<int N> __device__ __forceinline__ void waitvm(){
  if constexpr (N == 0) asm volatile("s_waitcnt vmcnt(0)" ::: "memory");
  else if constexpr (N == 4) asm volatile("s_waitcnt vmcnt(4)" ::: "memory");
  else if constexpr (N == 6) asm volatile("s_waitcnt vmcnt(6)" ::: "memory");
  else if constexpr (N == 8) asm volatile("s_waitcnt vmcnt(8)" ::: "memory");
}

__device__ __forceinline__ void barrier_pin(){
  __builtin_amdgcn_s_barrier();
  __builtin_amdgcn_sched_barrier(0);
}

__device__ __forceinline__ f32x4 mfma16(bf16x8 a, bf16x8 b, f32x4 c){
  return __builtin_amdgcn_mfma_f32_16x16x32_bf16(a, b, c, 0, 0, 0);
}
__device__ __forceinline__ f32x16 mfma32(bf16x8 a, bf16x8 b, f32x16 c){
  return __builtin_amdgcn_mfma_f32_32x32x16_bf16(a, b, c, 0, 0, 0);
}

__device__ __forceinline__ float exp2f_fast(float x){
#if __has_builtin(__builtin_amdgcn_exp2f)
  return __builtin_amdgcn_exp2f(x);
#else
  return __expf(x * 0.69314718056f);
#endif
}

__device__ __forceinline__ float gelu_f(float x){
  return 0.5f * x * (1.0f + erff(x * 0.70710678118654752f));
}

__device__ __forceinline__ void plane_swap(u32& a, u32& b){
  asm("v_permlane32_swap_b32 %0, %1" : "+v"(a), "+v"(b));
}
__device__ __forceinline__ u32 cvtpk_bf16(float lo, float hi){
  u32 r;
  asm("v_cvt_pk_bf16_f32 %0, %1, %2" : "=v"(r) : "v"(lo), "v"(hi));
  return r;
}

__device__ __forceinline__ bf16x8 ldlds(const u16* p){ return *(const bf16x8*)p; }

// ---------------- LayerNorm: fp32 row -> bf16 row ----------------
__global__ __launch_bounds__(256) void ln_kernel(const float* __restrict__ x,
    const float* __restrict__ g, const float* __restrict__ b, u16* __restrict__ out)
{
  int row = blockIdx.x;
  int tid = threadIdx.x;
  const float4* xr = (const float4*)(x + (size_t)row * Cc);
  float4 v = xr[tid];
  float s  = v.x + v.y + v.z + v.w;
  float s2 = v.x*v.x + v.y*v.y + v.z*v.z + v.w*v.w;
  #pragma unroll
  for (int off = 1; off < 64; off <<= 1){ s += __shfl_xor(s, off); s2 += __shfl_xor(s2, off); }
  __shared__ float red[8];
  int wid = tid >> 6;
  if ((tid & 63) == 0){ red[wid] = s; red[4 + wid] = s2; }
  __syncthreads();
  s  = red[0] + red[1] + red[2] + red[3];
  s2 = red[4] + red[5] + red[6] + red[7];
  float mu   = s * (1.0f / Cc);
  float var  = s2 * (1.0f / Cc) - mu * mu;
  float rstd = rsqrtf(var + 1e-5f);
  const float4 gg = ((const float4*)g)[tid];
  const float4 bb = ((const float4*)b)[tid];
  ushort4 o;
  o.x = f2bf((v.x - mu) * rstd * gg.x + bb.x);
  o.y = f2bf((v.y - mu) * rstd * gg.y + bb.y);
  o.z = f2bf((v.z - mu) * rstd * gg.z + bb.z);
  o.w = f2bf((v.w - mu) * rstd * gg.w + bb.w);
  *(ushort4*)(out + (size_t)row * Cc + tid * 4) = o;
}

// ---------------- transpose + cast: W[K][N] fp32 -> WT[N][K] bf16 ----------------
__global__ __launch_bounds__(256) void transpose_cast_kernel(const float* __restrict__ in,
    u16* __restrict__ out, int R, int Ccols)
{
  __shared__ float tile[32][33];
  int tx = threadIdx.x, ty = threadIdx.y;
  int c0 = blockIdx.x * 32, r0 = blockIdx.y * 32;
  #pragma unroll
  for (int j = 0; j < 4; j++) tile[ty + j*8][tx] = in[(size_t)(r0 + ty + j*8) * Ccols + c0 + tx];
  __syncthreads();
  #pragma unroll
  for (int j = 0; j < 4; j++) out[(size_t)(c0 + ty + j*8) * R + r0 + tx] = f2bf(tile[tx][ty + j*8]);
}

// ---------------- 4x fused 1024x1024 transpose+cast ----------------
__global__ __launch_bounds__(256) void transpose4_kernel(
    const float* __restrict__ s0, const float* __restrict__ s1,
    const float* __restrict__ s2, const float* __restrict__ s3,
    u16* __restrict__ d0, u16* __restrict__ d1, u16* __restrict__ d2, u16* __restrict__ d3)
{
  __shared__ float tile[32][33];
  int z = blockIdx.z;
  const float* in = (z == 0) ? s0 : (z == 1) ? s1 : (z == 2) ? s2 : s3;
  u16* out        = (z == 0) ? d0 : (z == 1) ? d1 : (z == 2) ? d2 : d3;
  int tx = threadIdx.x, ty = threadIdx.y;
  int c0 = blockIdx.x * 32, r0 = blockIdx.y * 32;
  #pragma unroll
  for (int j = 0; j < 4; j++) tile[ty + j*8][tx] = in[(size_t)(r0 + ty + j*8) * 1024 + c0 + tx];
  __syncthreads();
  #pragma unroll
  for (int j = 0; j < 4; j++) out[(size_t)(c0 + ty + j*8) * 1024 + r0 + tx] = f2bf(tile[tx][ty + j*8]);
}

// ---------------- pack 3 bias vectors into one [3072] ----------------
__global__ __launch_bounds__(256) void pack3_kernel(const float* __restrict__ a,
    const float* __restrict__ b, const float* __restrict__ c, float* __restrict__ o)
{
  int i = blockIdx.x * 256 + threadIdx.x;
  float v = (i < 1024) ? a[i] : (i < 2048 ? b[i - 1024] : c[i - 2048]);
  o[i] = v;
}

// ---------------- v slice of qkv (stride QS) -> vt (B,H,D,T) bf16 ----------------
__global__ __launch_bounds__(256) void transpose_v_kernel(const u16* __restrict__ v, u16* __restrict__ vt)
{
  __shared__ u16 tile[32][33];
  int tx = threadIdx.x, ty = threadIdx.y;
  int bh = blockIdx.z; int b = bh >> 4, h = bh & 15;
  int t0 = blockIdx.x * 32, d0 = blockIdx.y * 32;
  const u16* src = v + (size_t)b * Tt * QS + h * Dd;
  #pragma unroll
  for (int j = 0; j < 4; j++) tile[ty + j*8][tx] = src[(size_t)(t0 + ty + j*8) * QS + d0 + tx];
  __syncthreads();
  u16* dst = vt + (size_t)bh * Dd * Tt;
  #pragma unroll
  for (int j = 0; j < 4; j++) dst[(size_t)(d0 + ty + j*8) * Tt + t0 + tx] = tile[tx][ty + j*8];
}

// ======== BK=32 high-occupancy GEMM (T4+T2+T1), 128x128, 4 blocks/CU ========
// R16 retry with the spill fixed: __launch_bounds__(256,4) -> 128 VGPR budget
// (acc 64 + frags 32 + addressing ~20 fits; R16's (256,5) capped at ~102 -> 48 alloc
// -> accumulator spill -> 530MB scratch writes).
// EPI 2: bf16 (+bias, gelu); 3: bf16 (+bias, q-cols * QSCALE)
template<int EPI>
__global__ __launch_bounds__(256, 4) void gemm32_kernel(
    const u16* __restrict__ A, const u16* __restrict__ BT,
    const float* __restrict__ bias, void* __restrict__ out,
    int K, int ldA, int ldOut)
{
  __shared__ alignas(16) u16 As[2][128 * 32];
  __shared__ alignas(16) u16 Bs[2][128 * 32];

  const int tid  = threadIdx.x;
  const int lane = tid & 63, wid = tid >> 6;
  const int l15  = lane & 15, lg = lane >> 4;

  const int gx  = gridDim.x;
  const int lin = blockIdx.x + gx * blockIdx.y;
  const int nwg = gx * gridDim.y;
  const int wl  = (lin & 7) * (nwg >> 3) + (lin >> 3);
  const int rowBase = (wl % gx) * 128, colBase = (wl / gx) * 128;

  const int wr = wid >> 1, wc = wid & 1;

  f32x4 acc[4][4] = {};

  const int g0 = tid, g1 = tid + 256;
  const int r0 = g0 >> 2, w0 = (g0 & 3) ^ ((r0 >> 1) & 3);
  const int r1 = g1 >> 2, w1 = (g1 & 3) ^ ((r1 >> 1) & 3);
  const u16* pA0 = A  + (size_t)(rowBase + r0) * ldA + w0 * 8;
  const u16* pA1 = A  + (size_t)(rowBase + r1) * ldA + w1 * 8;
  const u16* pB0 = BT + (size_t)(colBase + r0) * K   + w0 * 8;
  const u16* pB1 = BT + (size_t)(colBase + r1) * K   + w1 * 8;
  const u32 d0 = (u32)g0 * 8, d1 = (u32)g1 * 8;

  u32 oa[4], ob[4];
  #pragma unroll
  for (int mi = 0; mi < 4; mi++){
    int r = wr * 64 + mi * 16 + l15;
    oa[mi] = (u32)(r * 32 + ((lg ^ ((r >> 1) & 3)) << 3));
  }
  #pragma unroll
  for (int ni = 0; ni < 4; ni++){
    int r = wc * 64 + ni * 16 + l15;
    ob[ni] = (u32)(r * 32 + ((lg ^ ((r >> 1) & 3)) << 3));
  }

  gl2lds16(pA0, &As[0][d0]); gl2lds16(pA1, &As[0][d1]);
  gl2lds16(pB0, &Bs[0][d0]); gl2lds16(pB1, &Bs[0][d1]);
  pA0 += 32; pA1 += 32; pB0 += 32; pB1 += 32;

  const int nt = K >> 5;
  #pragma unroll 2
  for (int t = 0; t < nt - 1; ++t){
    const int cur = t & 1, nxt = cur ^ 1;
    gl2lds16(pA0, &As[nxt][d0]); gl2lds16(pA1, &As[nxt][d1]);
    gl2lds16(pB0, &Bs[nxt][d0]); gl2lds16(pB1, &Bs[nxt][d1]);
    pA0 += 32; pA1 += 32; pB0 += 32; pB1 += 32;
    waitvm<4>();
    __builtin_amdgcn_s_barrier();
    __builtin_amdgcn_sched_barrier(0);

    bf16x8 afr[4], bfr[4];
    #pragma unroll
    for (int mi = 0; mi < 4; mi++) afr[mi] = ldlds(&As[cur][oa[mi]]);
    #pragma unroll
    for (int ni = 0; ni < 4; ni++) bfr[ni] = ldlds(&Bs[cur][ob[ni]]);
    __builtin_amdgcn_s_setprio(1);
    #pragma unroll
    for (int mi = 0; mi < 4; mi++)
      #pragma unroll
      for (int ni = 0; ni < 4; ni++)
        acc[mi][ni] = mfma16(afr[mi], bfr[ni], acc[mi][ni]);
    __builtin_amdgcn_s_setprio(0);

    __builtin_amdgcn_sched_barrier(0);
    __builtin_amdgcn_s_barrier();
  }
  {
    const int cur = (nt - 1) & 1;
    waitvm<0>();
    __builtin_amdgcn_s_barrier();
    bf16x8 afr[4], bfr[4];
    #pragma unroll
    for (int mi = 0; mi < 4; mi++) afr[mi] = ldlds(&As[cur][oa[mi]]);
    #pragma unroll
    for (int ni = 0; ni < 4; ni++) bfr[ni] = ldlds(&Bs[cur][ob[ni]]);
    #pragma unroll
    for (int mi = 0; mi < 4; mi++)
      #pragma unroll
      for (int ni = 0; ni < 4; ni++)
        acc[mi][ni] = mfma16(afr[mi], bfr[ni], acc[mi][ni]);
  }

  #pragma unroll
  for (int mi = 0; mi < 4; mi++){
    #pragma unroll
    for (int ni = 0; ni < 4; ni++){
      int row = rowBase + wr * 64 + mi * 16 + lg * 4;
      int col = colBase + wc * 64 + ni * 16 + l15;
      float bc = bias[col];
      #pragma unroll
      for (int r = 0; r < 4; r++){
        float val = acc[mi][ni][r] + bc;
        size_t idx = (size_t)(row + r) * ldOut + col;
        if constexpr (EPI == 2) ((u16*)out)[idx] = f2bf(gelu_f(val));
        else                    ((u16*)out)[idx] = f2bf(col < 1024 ? val * QSCALE : val);
      }
    }
  }
}

// ======== small-tile counted-vmcnt GEMM (T4+T2+T1), 64x64 BK=64 (Wo / W2) ========
// EPI 1: f32 out (+bias+residual)
template<int BM, int BN, int WPEU, int EPI>
__global__ __launch_bounds__(256, WPEU) void gemmc_kernel(
    const u16* __restrict__ A, const u16* __restrict__ BT,
    const float* __restrict__ bias, const float* __restrict__ resid,
    void* __restrict__ out, int K, int ldA, int ldOut)
{
  constexpr int MF = BM / 2 / 16;
  constexpr int NF = BN / 2 / 16;
  constexpr int AG = BM / 32;
  constexpr int BG = BN / 32;
  constexpr int NLOADS = AG + BG;

  __shared__ alignas(16) u16 As[2][BM * 64];
  __shared__ alignas(16) u16 Bs[2][BN * 64];

  const int tid  = threadIdx.x;
  const int lane = tid & 63, wid = tid >> 6;
  const int l15  = lane & 15, lg = lane >> 4;

  const int gx  = gridDim.x;
  const int lin = blockIdx.x + gx * blockIdx.y;
  const int nwg = gx * gridDim.y;
  const int wl  = (lin & 7) * (nwg >> 3) + (lin >> 3);
  const int rowBase = (wl % gx) * BM, colBase = (wl / gx) * BN;

  const int wr = wid >> 1, wc = wid & 1;

  f32x4 acc[MF][NF] = {};

  const u16* pA[AG];
  const u16* pB[BG];
  u32 dA[AG], dB[BG];
  #pragma unroll
  for (int j = 0; j < AG; j++){
    int g = tid + 256 * j;
    int r = g >> 3, w = (g & 7) ^ (r & 7);
    pA[j] = A + (size_t)(rowBase + r) * ldA + w * 8;
    dA[j] = (u32)g * 8;
  }
  #pragma unroll
  for (int j = 0; j < BG; j++){
    int g = tid + 256 * j;
    int r = g >> 3, w = (g & 7) ^ (r & 7);
    pB[j] = BT + (size_t)(colBase + r) * K + w * 8;
    dB[j] = (u32)g * 8;
  }

  u32 oa[MF][2], ob[NF][2];
  #pragma unroll
  for (int mi = 0; mi < MF; mi++){
    int r = wr * (BM / 2) + mi * 16 + l15;
    oa[mi][0] = (u32)(r * 64 + ((lg       ^ (r & 7)) << 3));
    oa[mi][1] = (u32)(r * 64 + (((4 + lg) ^ (r & 7)) << 3));
  }
  #pragma unroll
  for (int ni = 0; ni < NF; ni++){
    int r = wc * (BN / 2) + ni * 16 + l15;
    ob[ni][0] = (u32)(r * 64 + ((lg       ^ (r & 7)) << 3));
    ob[ni][1] = (u32)(r * 64 + (((4 + lg) ^ (r & 7)) << 3));
  }

  #pragma unroll
  for (int j = 0; j < AG; j++){ gl2lds16(pA[j], &As[0][dA[j]]); pA[j] += 64; }
  #pragma unroll
  for (int j = 0; j < BG; j++){ gl2lds16(pB[j], &Bs[0][dB[j]]); pB[j] += 64; }

  const int nt = K >> 6;
  #pragma unroll 2
  for (int t = 0; t < nt - 1; ++t){
    const int cur = t & 1, nxt = cur ^ 1;
    #pragma unroll
    for (int j = 0; j < AG; j++){ gl2lds16(pA[j], &As[nxt][dA[j]]); pA[j] += 64; }
    #pragma unroll
    for (int j = 0; j < BG; j++){ gl2lds16(pB[j], &Bs[nxt][dB[j]]); pB[j] += 64; }
    waitvm<NLOADS>();
    __builtin_amdgcn_s_barrier();
    __builtin_amdgcn_sched_barrier(0);

    bf16x8 afr[MF][2], bfr[NF][2];
    #pragma unroll
    for (int mi = 0; mi < MF; mi++){
      afr[mi][0] = ldlds(&As[cur][oa[mi][0]]);
      afr[mi][1] = ldlds(&As[cur][oa[mi][1]]);
    }
    #pragma unroll
    for (int ni = 0; ni < NF; ni++){
      bfr[ni][0] = ldlds(&Bs[cur][ob[ni][0]]);
      bfr[ni][1] = ldlds(&Bs[cur][ob[ni][1]]);
    }
    __builtin_amdgcn_s_setprio(1);
    #pragma unroll
    for (int mi = 0; mi < MF; mi++)
      #pragma unroll
      for (int ni = 0; ni < NF; ni++){
        acc[mi][ni] = mfma16(afr[mi][0], bfr[ni][0], acc[mi][ni]);
        acc[mi][ni] = mfma16(afr[mi][1], bfr[ni][1], acc[mi][ni]);
      }
    __builtin_amdgcn_s_setprio(0);

    __builtin_amdgcn_sched_barrier(0);
    __builtin_amdgcn_s_barrier();
  }
  {
    const int cur = (nt - 1) & 1;
    waitvm<0>();
    __builtin_amdgcn_s_barrier();
    bf16x8 afr[MF][2], bfr[NF][2];
    #pragma unroll
    for (int mi = 0; mi < MF; mi++){
      afr[mi][0] = ldlds(&As[cur][oa[mi][0]]);
      afr[mi][1] = ldlds(&As[cur][oa[mi][1]]);
    }
    #pragma unroll
    for (int ni = 0; ni < NF; ni++){
      bfr[ni][0] = ldlds(&Bs[cur][ob[ni][0]]);
      bfr[ni][1] = ldlds(&Bs[cur][ob[ni][1]]);
    }
    #pragma unroll
    for (int mi = 0; mi < MF; mi++)
      #pragma unroll
      for (int ni = 0; ni < NF; ni++){
        acc[mi][ni] = mfma16(afr[mi][0], bfr[ni][0], acc[mi][ni]);
        acc[mi][ni] = mfma16(afr[mi][1], bfr[ni][1], acc[mi][ni]);
      }
  }

  #pragma unroll
  for (int mi = 0; mi < MF; mi++){
    #pragma unroll
    for (int ni = 0; ni < NF; ni++){
      int row = rowBase + wr * (BM / 2) + mi * 16 + lg * 4;
      int col = colBase + wc * (BN / 2) + ni * 16 + l15;
      float bc = bias[col];
      #pragma unroll
      for (int r = 0; r < 4; r++){
        float val = acc[mi][ni][r] + bc;
        size_t idx = (size_t)(row + r) * ldOut + col;
        if constexpr (EPI == 1) ((float*)out)[idx] = val + resid[idx];
        else                    ((u16*)out)[idx]   = f2bf(val);
      }
    }
  }
}

// ---------------- Flash attention, swapped 32x32, KV-split x2 ----------------
__global__ __launch_bounds__(256, 4) void attn_kernel(const u16* __restrict__ q, const u16* __restrict__ k,
    const u16* __restrict__ vt, u16* __restrict__ opart, float* __restrict__ ml)
{
  __shared__ alignas(16) u16 Ks[2][64 * 64];
  __shared__ alignas(16) u16 Vs[2][64 * 64];
  int tid  = threadIdx.x;
  int lane = tid & 63, wid = tid >> 6;
  int l31  = lane & 31, hi = lane >> 5;

  int lin = blockIdx.x + 16 * blockIdx.y;
  int wl  = (lin & 7) * 64 + (lin >> 3);
  int qt  = wl & 15, bh = wl >> 4;
  int b = bh >> 4, h = bh & 15;
  int split = blockIdx.z;
  int kt0 = split * (Tt / 2);

  int qglob = qt * 128 + wid * 32 + l31;

  const u16* qp = q + ((size_t)b * Tt + qglob) * QS + h * Dd + hi * 8;
  bf16x8 qf[4];
  #pragma unroll
  for (int s = 0; s < 4; s++) qf[s] = *(const bf16x8*)(qp + s * 16);

  const u16* kbase = k  + (size_t)b * Tt * QS + h * Dd;
  const u16* vbase = vt + (size_t)bh * Dd * Tt;

  f32x16 yacc[2] = {};
  float m2 = -1e30f, lsum = 0.f;

  int g0 = tid, g1 = tid + 256;
  int r0 = g0 >> 3, cb0 = (g0 & 7) ^ (r0 & 7);
  int r1 = g1 >> 3, cb1 = (g1 & 7) ^ (r1 & 7);

  auto stageKV = [&](int buf, int kt){
    gl2lds16(kbase + (size_t)(kt + r0) * QS + cb0 * 8, (u16*)Ks[buf] + wid * 512);
    gl2lds16(kbase + (size_t)(kt + r1) * QS + cb1 * 8, (u16*)Ks[buf] + 2048 + wid * 512);
    gl2lds16(vbase + (size_t)r0 * Tt + kt + cb0 * 8,   (u16*)Vs[buf] + wid * 512);
    gl2lds16(vbase + (size_t)r1 * Tt + kt + cb1 * 8,   (u16*)Vs[buf] + 2048 + wid * 512);
  };

  stageKV(0, kt0);
  int cur = 0;
  for (int kt = kt0; kt < kt0 + Tt / 2; kt += 64) {
    if (kt + 64 < kt0 + Tt / 2) { stageKV(cur ^ 1, kt + 64); waitvm<4>(); }
    else                        { waitvm<0>(); }
    barrier_pin();

    const u16* Ksb = (const u16*)Ks[cur];
    const u16* Vsb = (const u16*)Vs[cur];
    int rx = l31 & 7;

    f32x16 st[2] = {};
    __builtin_amdgcn_s_setprio(1);
    #pragma unroll
    for (int nb = 0; nb < 2; nb++){
      const u16* krow = Ksb + (nb * 32 + l31) * 64;
      #pragma unroll
      for (int s = 0; s < 4; s++){
        bf16x8 kf = *(const bf16x8*)(krow + (((s * 2 + hi) ^ rx) << 3));
        st[nb] = mfma32(kf, qf[s], st[nb]);
      }
    }
    __builtin_amdgcn_s_setprio(0);

    float tm[16];
    #pragma unroll
    for (int i = 0; i < 16; i++) tm[i] = fmaxf(st[0][i], st[1][i]);
    #pragma unroll
    for (int w = 8; w; w >>= 1)
      #pragma unroll
      for (int i = 0; i < w; i++) tm[i] = fmaxf(tm[i], tm[i + w]);
    u32 ma = __builtin_bit_cast(u32, tm[0]), mb = ma;
    plane_swap(ma, mb);
    float mx = fmaxf(__builtin_bit_cast(float, ma), __builtin_bit_cast(float, mb));

    float mnew = fmaxf(m2, mx);
    float alpha = exp2f_fast(m2 - mnew);
    m2 = mnew;

    #pragma unroll
    for (int nb = 0; nb < 2; nb++)
      #pragma unroll
      for (int i = 0; i < 16; i++)
        st[nb][i] = exp2f_fast(st[nb][i] - m2);

    float ts[16];
    #pragma unroll
    for (int i = 0; i < 16; i++) ts[i] = st[0][i] + st[1][i];
    #pragma unroll
    for (int w = 8; w; w >>= 1)
      #pragma unroll
      for (int i = 0; i < w; i++) ts[i] += ts[i + w];
    u32 sa = __builtin_bit_cast(u32, ts[0]), sb = sa;
    plane_swap(sa, sb);
    lsum = lsum * alpha + __builtin_bit_cast(float, sa) + __builtin_bit_cast(float, sb);

    #pragma unroll
    for (int nd = 0; nd < 2; nd++)
      #pragma unroll
      for (int i = 0; i < 16; i++) yacc[nd][i] *= alpha;

    bf16x8 pb[4];
    #pragma unroll
    for (int nb = 0; nb < 2; nb++){
      u32 c[8];
      #pragma unroll
      for (int i = 0; i < 8; i++) c[i] = cvtpk_bf16(st[nb][2 * i], st[nb][2 * i + 1]);
      plane_swap(c[0], c[2]); plane_swap(c[1], c[3]);
      plane_swap(c[4], c[6]); plane_swap(c[5], c[7]);
      u32 f0[4] = {c[0], c[1], c[2], c[3]};
      u32 f1[4] = {c[4], c[5], c[6], c[7]};
      pb[nb * 2 + 0] = *(bf16x8*)f0;
      pb[nb * 2 + 1] = *(bf16x8*)f1;
    }

    __builtin_amdgcn_s_setprio(1);
    #pragma unroll
    for (int nd = 0; nd < 2; nd++){
      const u16* vrow = Vsb + (nd * 32 + l31) * 64;
      #pragma unroll
      for (int ks = 0; ks < 4; ks++){
        bf16x8 vf = *(const bf16x8*)(vrow + (((ks * 2 + hi) ^ rx) << 3));
        yacc[nd] = mfma32(vf, pb[ks], yacc[nd]);
      }
    }
    __builtin_amdgcn_s_setprio(0);

    __builtin_amdgcn_sched_barrier(0);
    barrier_pin();
    cur ^= 1;
  }

  float inv = 1.0f / lsum;
  u16* op = opart + ((size_t)split * (Bb * Tt) + (size_t)b * Tt + qglob) * Cc + h * Dd;
  #pragma unroll
  for (int nd = 0; nd < 2; nd++){
    #pragma unroll
    for (int g = 0; g < 4; g++){
      ushort4 o;
      o.x = f2bf(yacc[nd][g * 4 + 0] * inv);
      o.y = f2bf(yacc[nd][g * 4 + 1] * inv);
      o.z = f2bf(yacc[nd][g * 4 + 2] * inv);
      o.w = f2bf(yacc[nd][g * 4 + 3] * inv);
      *(ushort4*)(op + nd * 32 + g * 8 + hi * 4) = o;
    }
  }
  if (hi == 0){
    float* mlp = ml + (((size_t)split * (Bb * Tt) + (size_t)b * Tt + qglob) * Hh + h) * 2;
    mlp[0] = m2; mlp[1] = lsum;
  }
}

// ---------------- combine 2 KV-splits (convex combination of normalized partials) ----
__global__ __launch_bounds__(256) void combine_kernel(const u16* __restrict__ opart,
    const float* __restrict__ ml, u16* __restrict__ y)
{
  int row = blockIdx.x;
  int d0  = threadIdx.x * 4;
  int h   = d0 >> 6;
  const float* p0 = ml + ((size_t)row * Hh + h) * 2;
  const float* p1 = ml + (((size_t)(Bb * Tt) + row) * Hh + h) * 2;
  float m0 = p0[0], l0 = p0[1], m1 = p1[0], l1 = p1[1];
  float M  = fmaxf(m0, m1);
  float u0 = l0 * exp2f_fast(m0 - M), u1 = l1 * exp2f_fast(m1 - M);
  float inv = 1.0f / (u0 + u1);
  float w0 = u0 * inv, w1 = u1 * inv;
  ushort4 a = *(const ushort4*)(opart + (size_t)row * Cc + d0);
  ushort4 c = *(const ushort4*)(opart + ((size_t)(Bb * Tt) + row) * Cc + d0);
  ushort4 o;
  o.x = f2bf(bf2f(a.x) * w0 + bf2f(c.x) * w1);
  o.y = f2bf(bf2f(a.y) * w0 + bf2f(c.y) * w1);
  o.z = f2bf(bf2f(a.z) * w0 + bf2f(c.z) * w1);
  o.w = f2bf(bf2f(a.w) * w0 + bf2f(c.w) * w1);
  *(ushort4*)(y + (size_t)row * Cc + d0) = o;
}

extern "C" void kernel_launch(void* const* d_in, const int* in_sizes, int n_in,
                              void* d_out, int out_size, void* d_ws, size_t ws_size,
                              hipStream_t stream)
{
  (void)in_sizes; (void)n_in; (void)out_size; (void)ws_size;
  const float* x    = (const float*)d_in[0];
  const float* Wq   = (const float*)d_in[1];
  const float* bq   = (const float*)d_in[2];
  const float* Wk   = (const float*)d_in[3];
  const float* bk   = (const float*)d_in[4];
  const float* Wv   = (const float*)d_in[5];
  const float* bv   = (const float*)d_in[6];
  const float* Wo   = (const float*)d_in[7];
  const float* bo   = (const float*)d_in[8];
  const float* ln1g = (const float*)d_in[9];
  const float* ln1b = (const float*)d_in[10];
  const float* ln2g = (const float*)d_in[11];
  const float* ln2b = (const float*)d_in[12];
  const float* W1   = (const float*)d_in[13];
  const float* b1   = (const float*)d_in[14];
  const float* W2   = (const float*)d_in[15];
  const float* b2   = (const float*)d_in[16];

  char* ws = (char*)d_ws;
  const size_t MB = 1024 * 1024;
  u16*   wqkvt = (u16*)(ws + 0 * MB);      // 6 MB  (Wq^T | Wk^T | Wv^T rows)
  u16*   wot   = (u16*)(ws + 6 * MB);      // 2 MB
  u16*   w1t   = (u16*)(ws + 8 * MB);      // 8 MB
  u16*   w2t   = (u16*)(ws + 16 * MB);     // 8 MB
  float* bqkv  = (float*)(ws + 24 * MB);   // 12 KB
  u16*   hbuf  = (u16*)(ws + 25 * MB);     // 8 MB  (h2 overlays after QKV gemm)
  u16*   qkv   = (u16*)(ws + 33 * MB);     // 24 MB (mb overlays 33..65 after attn)
  u16*   vtb   = (u16*)(ws + 57 * MB);     // 8 MB
  u16*   yb    = (u16*)(ws + 65 * MB);     // 8 MB
  u16*   opart = (u16*)(ws + 73 * MB);     // 16 MB (2 splits x 8 MB)
  float* x2    = (float*)(ws + 73 * MB);   // 16 MB (written by Wo gemm, after combine)
  float* mlb   = (float*)(ws + 89 * MB);   // 1 MB
  u16*   h2    = hbuf;
  u16*   mb    = qkv;

  dim3 tb(32, 8);
  transpose4_kernel<<<dim3(32, 32, 4), tb, 0, stream>>>(Wq, Wk, Wv, Wo,
      wqkvt, wqkvt + 1024 * 1024, wqkvt + 2048 * 1024, wot);
  transpose_cast_kernel<<<dim3(128, 32), tb, 0, stream>>>(W1, w1t, 1024, 4096);
  transpose_cast_kernel<<<dim3(32, 128), tb, 0, stream>>>(W2, w2t, 4096, 1024);
  pack3_kernel<<<12, 256, 0, stream>>>(bq, bk, bv, bqkv);

  ln_kernel<<<4096, 256, 0, stream>>>(x, ln1g, ln1b, hbuf);

  // fused QKV: 128x128 BK=32, 768 blocks, 4 blocks/CU (EPI 3: q cols pre-scaled)
  gemm32_kernel<3><<<dim3(32, 24), 256, 0, stream>>>(hbuf, wqkvt, bqkv, qkv, 1024, 1024, 3072);

  transpose_v_kernel<<<dim3(64, 2, 32), tb, 0, stream>>>(qkv + 2048, vtb);

  // KV-split x2 attention + combine
  attn_kernel<<<dim3(16, 32, 2), 256, 0, stream>>>(qkv, qkv + 1024, vtb, opart, mlb);
  combine_kernel<<<4096, 256, 0, stream>>>(opart, mlb, yb);

  // Wo: 64x64 tiles, 1024 blocks, 4 blocks/CU
  gemmc_kernel<64, 64, 4, 1><<<dim3(64, 16), 256, 0, stream>>>(yb, wot, bo, x, x2, 1024, 1024, 1024);

  ln_kernel<<<4096, 256, 0, stream>>>(x2, ln2g, ln2b, h2);

  // W1: 128x128 BK=32, 1024 blocks, 4 blocks/CU (gelu)
  gemm32_kernel<2><<<dim3(32, 32), 256, 0, stream>>>(h2, w1t, b1, mb, 1024, 1024, 4096);

  // W2: 64x64 tiles BK=64, 1024 blocks, 4 blocks/CU (R13 proven)
  gemmc_kernel<64, 64, 4, 1><<<dim3(64, 16), 256, 0, stream>>>(mb, w2t, b2, x2, (float*)d_out, 4096, 4096, 1024);
}

// Round 18
// 242.841 us; speedup vs baseline: 1.8772x; 1.0155x over previous
//
#include <hip/hip_runtime.h>
#include <math.h>

typedef unsigned short u16;
typedef unsigned int   u32;
using bf16x8 = __attribute__((ext_vector_type(8))) short;
using f32x4  = __attribute__((ext_vector_type(4))) float;
using f32x16 = __attribute__((ext_vector_type(16))) float;

static constexpr int Bb = 2, Tt = 2048, Cc = 1024, Hh = 16, Dd = 64;
static constexpr int QS = 3072;   // fused qkv row stride (u16 elements)
static constexpr float QSCALE = 0.125f * 1.44269504089f;  // folded into Q at QKV epilogue

__device__ __forceinline__ u16 f2bf(float f){
  u32 u = __builtin_bit_cast(u32, f);
  u += 0x7fffu + ((u >> 16) & 1u);
  return (u16)(u >> 16);
}
__device__ __forceinline__ float bf2f(u16 v){
  u32 u = (u32)v << 16;
  return __builtin_bit_cast(float, u);
}

__device__ __forceinline__ void gl2lds16(const void* g, void* l){
  __builtin_amdgcn_global_load_lds((const __attribute__((address_space(1))) void*)g,
                                   (__attribute__((address_space(3))) void*)l, 16, 0, 0);
}

template<int N> __device__ __forceinline__ void waitvm(){
  if constexpr (N == 0) asm volatile("s_waitcnt vmcnt(0)" ::: "memory");
  else if constexpr (N == 4) asm volatile("s_waitcnt vmcnt(4)" ::: "memory");
  else if constexpr (N == 6) asm volatile("s_waitcnt vmcnt(6)" ::: "memory");
  else if constexpr (N == 8) asm volatile("s_waitcnt vmcnt(8)" ::: "memory");
}

__device__ __forceinline__ void barrier_pin(){
  __builtin_amdgcn_s_barrier();
  __builtin_amdgcn_sched_barrier(0);
}

__device__ __forceinline__ f32x4 mfma16(bf16x8 a, bf16x8 b, f32x4 c){
  return __builtin_amdgcn_mfma_f32_16x16x32_bf16(a, b, c, 0, 0, 0);
}
__device__ __forceinline__ f32x16 mfma32(bf16x8 a, bf16x8 b, f32x16 c){
  return __builtin_amdgcn_mfma_f32_32x32x16_bf16(a, b, c, 0, 0, 0);
}

__device__ __forceinline__ float exp2f_fast(float x){
#if __has_builtin(__builtin_amdgcn_exp2f)
  return __builtin_amdgcn_exp2f(x);
#else
  return __expf(x * 0.69314718056f);
#endif
}

__device__ __forceinline__ float gelu_f(float x){
  return 0.5f * x * (1.0f + erff(x * 0.70710678118654752f));
}

__device__ __forceinline__ float fmax3(float a, float b, float c){
  return fmaxf(fmaxf(a, b), c);   // clang fuses to v_max3_f32
}

__device__ __forceinline__ void plane_swap(u32& a, u32& b){
  asm("v_permlane32_swap_b32 %0, %1" : "+v"(a), "+v"(b));
}
__device__ __forceinline__ u32 cvtpk_bf16(float lo, float hi){
  u32 r;
  asm("v_cvt_pk_bf16_f32 %0, %1, %2" : "=v"(r) : "v"(lo), "v"(hi));
  return r;
}

__device__ __forceinline__ bf16x8 ldlds(const u16* p){ return *(const bf16x8*)p; }

// ---------------- LayerNorm: fp32 row -> bf16 row ----------------
__global__ __launch_bounds__(256) void ln_kernel(const float* __restrict__ x,
    const float* __restrict__ g, const float* __restrict__ b, u16* __restrict__ out)
{
  int row = blockIdx.x;
  int tid = threadIdx.x;
  const float4* xr = (const float4*)(x + (size_t)row * Cc);
  float4 v = xr[tid];
  float s  = v.x + v.y + v.z + v.w;
  float s2 = v.x*v.x + v.y*v.y + v.z*v.z + v.w*v.w;
  #pragma unroll
  for (int off = 1; off < 64; off <<= 1){ s += __shfl_xor(s, off); s2 += __shfl_xor(s2, off); }
  __shared__ float red[8];
  int wid = tid >> 6;
  if ((tid & 63) == 0){ red[wid] = s; red[4 + wid] = s2; }
  __syncthreads();
  s  = red[0] + red[1] + red[2] + red[3];
  s2 = red[4] + red[5] + red[6] + red[7];
  float mu   = s * (1.0f / Cc);
  float var  = s2 * (1.0f / Cc) - mu * mu;
  float rstd = rsqrtf(var + 1e-5f);
  const float4 gg = ((const float4*)g)[tid];
  const float4 bb = ((const float4*)b)[tid];
  ushort4 o;
  o.x = f2bf((v.x - mu) * rstd * gg.x + bb.x);
  o.y = f2bf((v.y - mu) * rstd * gg.y + bb.y);
  o.z = f2bf((v.z - mu) * rstd * gg.z + bb.z);
  o.w = f2bf((v.w - mu) * rstd * gg.w + bb.w);
  *(ushort4*)(out + (size_t)row * Cc + tid * 4) = o;
}

// ---------------- transpose + cast: W[K][N] fp32 -> WT[N][K] bf16 ----------------
__global__ __launch_bounds__(256) void transpose_cast_kernel(const float* __restrict__ in,
    u16* __restrict__ out, int R, int Ccols)
{
  __shared__ float tile[32][33];
  int tx = threadIdx.x, ty = threadIdx.y;
  int c0 = blockIdx.x * 32, r0 = blockIdx.y * 32;
  #pragma unroll
  for (int j = 0; j < 4; j++) tile[ty + j*8][tx] = in[(size_t)(r0 + ty + j*8) * Ccols + c0 + tx];
  __syncthreads();
  #pragma unroll
  for (int j = 0; j < 4; j++) out[(size_t)(c0 + ty + j*8) * R + r0 + tx] = f2bf(tile[tx][ty + j*8]);
}

// ---------------- 4x fused 1024x1024 transpose+cast ----------------
__global__ __launch_bounds__(256) void transpose4_kernel(
    const float* __restrict__ s0, const float* __restrict__ s1,
    const float* __restrict__ s2, const float* __restrict__ s3,
    u16* __restrict__ d0, u16* __restrict__ d1, u16* __restrict__ d2, u16* __restrict__ d3)
{
  __shared__ float tile[32][33];
  int z = blockIdx.z;
  const float* in = (z == 0) ? s0 : (z == 1) ? s1 : (z == 2) ? s2 : s3;
  u16* out        = (z == 0) ? d0 : (z == 1) ? d1 : (z == 2) ? d2 : d3;
  int tx = threadIdx.x, ty = threadIdx.y;
  int c0 = blockIdx.x * 32, r0 = blockIdx.y * 32;
  #pragma unroll
  for (int j = 0; j < 4; j++) tile[ty + j*8][tx] = in[(size_t)(r0 + ty + j*8) * 1024 + c0 + tx];
  __syncthreads();
  #pragma unroll
  for (int j = 0; j < 4; j++) out[(size_t)(c0 + ty + j*8) * 1024 + r0 + tx] = f2bf(tile[tx][ty + j*8]);
}

// ---------------- pack 3 bias vectors into one [3072] ----------------
__global__ __launch_bounds__(256) void pack3_kernel(const float* __restrict__ a,
    const float* __restrict__ b, const float* __restrict__ c, float* __restrict__ o)
{
  int i = blockIdx.x * 256 + threadIdx.x;
  float v = (i < 1024) ? a[i] : (i < 2048 ? b[i - 1024] : c[i - 2048]);
  o[i] = v;
}

// ---------------- v slice of qkv (stride QS) -> vt (B,H,D,T) bf16 ----------------
__global__ __launch_bounds__(256) void transpose_v_kernel(const u16* __restrict__ v, u16* __restrict__ vt)
{
  __shared__ u16 tile[32][33];
  int tx = threadIdx.x, ty = threadIdx.y;
  int bh = blockIdx.z; int b = bh >> 4, h = bh & 15;
  int t0 = blockIdx.x * 32, d0 = blockIdx.y * 32;
  const u16* src = v + (size_t)b * Tt * QS + h * Dd;
  #pragma unroll
  for (int j = 0; j < 4; j++) tile[ty + j*8][tx] = src[(size_t)(t0 + ty + j*8) * QS + d0 + tx];
  __syncthreads();
  u16* dst = vt + (size_t)bh * Dd * Tt;
  #pragma unroll
  for (int j = 0; j < 4; j++) dst[(size_t)(d0 + ty + j*8) * Tt + t0 + tx] = tile[tx][ty + j*8];
}

// ======== BK=32 high-occupancy GEMM (T4+T2+T1), 128x128, 4 blocks/CU (R17-exact) ====
// EPI 2: bf16 (+bias, gelu); 3: bf16 (+bias, q-cols * QSCALE)
template<int EPI>
__global__ __launch_bounds__(256, 4) void gemm32_kernel(
    const u16* __restrict__ A, const u16* __restrict__ BT,
    const float* __restrict__ bias, void* __restrict__ out,
    int K, int ldA, int ldOut)
{
  __shared__ alignas(16) u16 As[2][128 * 32];
  __shared__ alignas(16) u16 Bs[2][128 * 32];

  const int tid  = threadIdx.x;
  const int lane = tid & 63, wid = tid >> 6;
  const int l15  = lane & 15, lg = lane >> 4;

  const int gx  = gridDim.x;
  const int lin = blockIdx.x + gx * blockIdx.y;
  const int nwg = gx * gridDim.y;
  const int wl  = (lin & 7) * (nwg >> 3) + (lin >> 3);
  const int rowBase = (wl % gx) * 128, colBase = (wl / gx) * 128;

  const int wr = wid >> 1, wc = wid & 1;

  f32x4 acc[4][4] = {};

  const int g0 = tid, g1 = tid + 256;
  const int r0 = g0 >> 2, w0 = (g0 & 3) ^ ((r0 >> 1) & 3);
  const int r1 = g1 >> 2, w1 = (g1 & 3) ^ ((r1 >> 1) & 3);
  const u16* pA0 = A  + (size_t)(rowBase + r0) * ldA + w0 * 8;
  const u16* pA1 = A  + (size_t)(rowBase + r1) * ldA + w1 * 8;
  const u16* pB0 = BT + (size_t)(colBase + r0) * K   + w0 * 8;
  const u16* pB1 = BT + (size_t)(colBase + r1) * K   + w1 * 8;
  const u32 d0 = (u32)g0 * 8, d1 = (u32)g1 * 8;

  u32 oa[4], ob[4];
  #pragma unroll
  for (int mi = 0; mi < 4; mi++){
    int r = wr * 64 + mi * 16 + l15;
    oa[mi] = (u32)(r * 32 + ((lg ^ ((r >> 1) & 3)) << 3));
  }
  #pragma unroll
  for (int ni = 0; ni < 4; ni++){
    int r = wc * 64 + ni * 16 + l15;
    ob[ni] = (u32)(r * 32 + ((lg ^ ((r >> 1) & 3)) << 3));
  }

  gl2lds16(pA0, &As[0][d0]); gl2lds16(pA1, &As[0][d1]);
  gl2lds16(pB0, &Bs[0][d0]); gl2lds16(pB1, &Bs[0][d1]);
  pA0 += 32; pA1 += 32; pB0 += 32; pB1 += 32;

  const int nt = K >> 5;
  #pragma unroll 2
  for (int t = 0; t < nt - 1; ++t){
    const int cur = t & 1, nxt = cur ^ 1;
    gl2lds16(pA0, &As[nxt][d0]); gl2lds16(pA1, &As[nxt][d1]);
    gl2lds16(pB0, &Bs[nxt][d0]); gl2lds16(pB1, &Bs[nxt][d1]);
    pA0 += 32; pA1 += 32; pB0 += 32; pB1 += 32;
    waitvm<4>();
    __builtin_amdgcn_s_barrier();
    __builtin_amdgcn_sched_barrier(0);

    bf16x8 afr[4], bfr[4];
    #pragma unroll
    for (int mi = 0; mi < 4; mi++) afr[mi] = ldlds(&As[cur][oa[mi]]);
    #pragma unroll
    for (int ni = 0; ni < 4; ni++) bfr[ni] = ldlds(&Bs[cur][ob[ni]]);
    __builtin_amdgcn_s_setprio(1);
    #pragma unroll
    for (int mi = 0; mi < 4; mi++)
      #pragma unroll
      for (int ni = 0; ni < 4; ni++)
        acc[mi][ni] = mfma16(afr[mi], bfr[ni], acc[mi][ni]);
    __builtin_amdgcn_s_setprio(0);

    __builtin_amdgcn_sched_barrier(0);
    __builtin_amdgcn_s_barrier();
  }
  {
    const int cur = (nt - 1) & 1;
    waitvm<0>();
    __builtin_amdgcn_s_barrier();
    bf16x8 afr[4], bfr[4];
    #pragma unroll
    for (int mi = 0; mi < 4; mi++) afr[mi] = ldlds(&As[cur][oa[mi]]);
    #pragma unroll
    for (int ni = 0; ni < 4; ni++) bfr[ni] = ldlds(&Bs[cur][ob[ni]]);
    #pragma unroll
    for (int mi = 0; mi < 4; mi++)
      #pragma unroll
      for (int ni = 0; ni < 4; ni++)
        acc[mi][ni] = mfma16(afr[mi], bfr[ni], acc[mi][ni]);
  }

  #pragma unroll
  for (int mi = 0; mi < 4; mi++){
    #pragma unroll
    for (int ni = 0; ni < 4; ni++){
      int row = rowBase + wr * 64 + mi * 16 + lg * 4;
      int col = colBase + wc * 64 + ni * 16 + l15;
      float bc = bias[col];
      #pragma unroll
      for (int r = 0; r < 4; r++){
        float val = acc[mi][ni][r] + bc;
        size_t idx = (size_t)(row + r) * ldOut + col;
        if constexpr (EPI == 2) ((u16*)out)[idx] = f2bf(gelu_f(val));
        else                    ((u16*)out)[idx] = f2bf(col < 1024 ? val * QSCALE : val);
      }
    }
  }
}

// ======== small-tile counted-vmcnt GEMM (T4+T2+T1), 64x64 BK=64 (Wo / W2) ========
// EPI 1: f32 out (+bias+residual)
template<int BM, int BN, int WPEU, int EPI>
__global__ __launch_bounds__(256, WPEU) void gemmc_kernel(
    const u16* __restrict__ A, const u16* __restrict__ BT,
    const float* __restrict__ bias, const float* __restrict__ resid,
    void* __restrict__ out, int K, int ldA, int ldOut)
{
  constexpr int MF = BM / 2 / 16;
  constexpr int NF = BN / 2 / 16;
  constexpr int AG = BM / 32;
  constexpr int BG = BN / 32;
  constexpr int NLOADS = AG + BG;

  __shared__ alignas(16) u16 As[2][BM * 64];
  __shared__ alignas(16) u16 Bs[2][BN * 64];

  const int tid  = threadIdx.x;
  const int lane = tid & 63, wid = tid >> 6;
  const int l15  = lane & 15, lg = lane >> 4;

  const int gx  = gridDim.x;
  const int lin = blockIdx.x + gx * blockIdx.y;
  const int nwg = gx * gridDim.y;
  const int wl  = (lin & 7) * (nwg >> 3) + (lin >> 3);
  const int rowBase = (wl % gx) * BM, colBase = (wl / gx) * BN;

  const int wr = wid >> 1, wc = wid & 1;

  f32x4 acc[MF][NF] = {};

  const u16* pA[AG];
  const u16* pB[BG];
  u32 dA[AG], dB[BG];
  #pragma unroll
  for (int j = 0; j < AG; j++){
    int g = tid + 256 * j;
    int r = g >> 3, w = (g & 7) ^ (r & 7);
    pA[j] = A + (size_t)(rowBase + r) * ldA + w * 8;
    dA[j] = (u32)g * 8;
  }
  #pragma unroll
  for (int j = 0; j < BG; j++){
    int g = tid + 256 * j;
    int r = g >> 3, w = (g & 7) ^ (r & 7);
    pB[j] = BT + (size_t)(colBase + r) * K + w * 8;
    dB[j] = (u32)g * 8;
  }

  u32 oa[MF][2], ob[NF][2];
  #pragma unroll
  for (int mi = 0; mi < MF; mi++){
    int r = wr * (BM / 2) + mi * 16 + l15;
    oa[mi][0] = (u32)(r * 64 + ((lg       ^ (r & 7)) << 3));
    oa[mi][1] = (u32)(r * 64 + (((4 + lg) ^ (r & 7)) << 3));
  }
  #pragma unroll
  for (int ni = 0; ni < NF; ni++){
    int r = wc * (BN / 2) + ni * 16 + l15;
    ob[ni][0] = (u32)(r * 64 + ((lg       ^ (r & 7)) << 3));
    ob[ni][1] = (u32)(r * 64 + (((4 + lg) ^ (r & 7)) << 3));
  }

  #pragma unroll
  for (int j = 0; j < AG; j++){ gl2lds16(pA[j], &As[0][dA[j]]); pA[j] += 64; }
  #pragma unroll
  for (int j = 0; j < BG; j++){ gl2lds16(pB[j], &Bs[0][dB[j]]); pB[j] += 64; }

  const int nt = K >> 6;
  #pragma unroll 2
  for (int t = 0; t < nt - 1; ++t){
    const int cur = t & 1, nxt = cur ^ 1;
    #pragma unroll
    for (int j = 0; j < AG; j++){ gl2lds16(pA[j], &As[nxt][dA[j]]); pA[j] += 64; }
    #pragma unroll
    for (int j = 0; j < BG; j++){ gl2lds16(pB[j], &Bs[nxt][dB[j]]); pB[j] += 64; }
    waitvm<NLOADS>();
    __builtin_amdgcn_s_barrier();
    __builtin_amdgcn_sched_barrier(0);

    bf16x8 afr[MF][2], bfr[NF][2];
    #pragma unroll
    for (int mi = 0; mi < MF; mi++){
      afr[mi][0] = ldlds(&As[cur][oa[mi][0]]);
      afr[mi][1] = ldlds(&As[cur][oa[mi][1]]);
    }
    #pragma unroll
    for (int ni = 0; ni < NF; ni++){
      bfr[ni][0] = ldlds(&Bs[cur][ob[ni][0]]);
      bfr[ni][1] = ldlds(&Bs[cur][ob[ni][1]]);
    }
    __builtin_amdgcn_s_setprio(1);
    #pragma unroll
    for (int mi = 0; mi < MF; mi++)
      #pragma unroll
      for (int ni = 0; ni < NF; ni++){
        acc[mi][ni] = mfma16(afr[mi][0], bfr[ni][0], acc[mi][ni]);
        acc[mi][ni] = mfma16(afr[mi][1], bfr[ni][1], acc[mi][ni]);
      }
    __builtin_amdgcn_s_setprio(0);

    __builtin_amdgcn_sched_barrier(0);
    __builtin_amdgcn_s_barrier();
  }
  {
    const int cur = (nt - 1) & 1;
    waitvm<0>();
    __builtin_amdgcn_s_barrier();
    bf16x8 afr[MF][2], bfr[NF][2];
    #pragma unroll
    for (int mi = 0; mi < MF; mi++){
      afr[mi][0] = ldlds(&As[cur][oa[mi][0]]);
      afr[mi][1] = ldlds(&As[cur][oa[mi][1]]);
    }
    #pragma unroll
    for (int ni = 0; ni < NF; ni++){
      bfr[ni][0] = ldlds(&Bs[cur][ob[ni][0]]);
      bfr[ni][1] = ldlds(&Bs[cur][ob[ni][1]]);
    }
    #pragma unroll
    for (int mi = 0; mi < MF; mi++)
      #pragma unroll
      for (int ni = 0; ni < NF; ni++){
        acc[mi][ni] = mfma16(afr[mi][0], bfr[ni][0], acc[mi][ni]);
        acc[mi][ni] = mfma16(afr[mi][1], bfr[ni][1], acc[mi][ni]);
      }
  }

  #pragma unroll
  for (int mi = 0; mi < MF; mi++){
    #pragma unroll
    for (int ni = 0; ni < NF; ni++){
      int row = rowBase + wr * (BM / 2) + mi * 16 + lg * 4;
      int col = colBase + wc * (BN / 2) + ni * 16 + l15;
      float bc = bias[col];
      #pragma unroll
      for (int r = 0; r < 4; r++){
        float val = acc[mi][ni][r] + bc;
        size_t idx = (size_t)(row + r) * ldOut + col;
        if constexpr (EPI == 1) ((float*)out)[idx] = val + resid[idx];
        else                    ((u16*)out)[idx]   = f2bf(val);
      }
    }
  }
}

// ---------------- Flash attention, swapped 32x32, KV-split x2 ----------------
// v2: defer-max (T13, THR=8 exp2-domain), max3 reduce tree, row-sum via MFMA
// ones-operand on the underused matrix pipe (replaces the 31-op VALU sum tree).
__global__ __launch_bounds__(256, 4) void attn_kernel(const u16* __restrict__ q, const u16* __restrict__ k,
    const u16* __restrict__ vt, u16* __restrict__ opart, float* __restrict__ ml)
{
  __shared__ alignas(16) u16 Ks[2][64 * 64];
  __shared__ alignas(16) u16 Vs[2][64 * 64];
  int tid  = threadIdx.x;
  int lane = tid & 63, wid = tid >> 6;
  int l31  = lane & 31, hi = lane >> 5;

  int lin = blockIdx.x + 16 * blockIdx.y;
  int wl  = (lin & 7) * 64 + (lin >> 3);
  int qt  = wl & 15, bh = wl >> 4;
  int b = bh >> 4, h = bh & 15;
  int split = blockIdx.z;
  int kt0 = split * (Tt / 2);

  int qglob = qt * 128 + wid * 32 + l31;

  const u16* qp = q + ((size_t)b * Tt + qglob) * QS + h * Dd + hi * 8;
  bf16x8 qf[4];
  #pragma unroll
  for (int s = 0; s < 4; s++) qf[s] = *(const bf16x8*)(qp + s * 16);

  bf16x8 ones;
  #pragma unroll
  for (int i = 0; i < 8; i++) ones[i] = (short)0x3F80;   // bf16 1.0

  const u16* kbase = k  + (size_t)b * Tt * QS + h * Dd;
  const u16* vbase = vt + (size_t)bh * Dd * Tt;

  f32x16 yacc[2] = {};
  float m2 = -1e30f, lsum = 0.f;

  int g0 = tid, g1 = tid + 256;
  int r0 = g0 >> 3, cb0 = (g0 & 7) ^ (r0 & 7);
  int r1 = g1 >> 3, cb1 = (g1 & 7) ^ (r1 & 7);

  auto stageKV = [&](int buf, int kt){
    gl2lds16(kbase + (size_t)(kt + r0) * QS + cb0 * 8, (u16*)Ks[buf] + wid * 512);
    gl2lds16(kbase + (size_t)(kt + r1) * QS + cb1 * 8, (u16*)Ks[buf] + 2048 + wid * 512);
    gl2lds16(vbase + (size_t)r0 * Tt + kt + cb0 * 8,   (u16*)Vs[buf] + wid * 512);
    gl2lds16(vbase + (size_t)r1 * Tt + kt + cb1 * 8,   (u16*)Vs[buf] + 2048 + wid * 512);
  };

  stageKV(0, kt0);
  int cur = 0;
  for (int kt = kt0; kt < kt0 + Tt / 2; kt += 64) {
    if (kt + 64 < kt0 + Tt / 2) { stageKV(cur ^ 1, kt + 64); waitvm<4>(); }
    else                        { waitvm<0>(); }
    barrier_pin();

    const u16* Ksb = (const u16*)Ks[cur];
    const u16* Vsb = (const u16*)Vs[cur];
    int rx = l31 & 7;

    // ---- QK^T (swapped): st in exp2 domain (Q pre-scaled)
    f32x16 st[2] = {};
    __builtin_amdgcn_s_setprio(1);
    #pragma unroll
    for (int nb = 0; nb < 2; nb++){
      const u16* krow = Ksb + (nb * 32 + l31) * 64;
      #pragma unroll
      for (int s = 0; s < 4; s++){
        bf16x8 kf = *(const bf16x8*)(krow + (((s * 2 + hi) ^ rx) << 3));
        st[nb] = mfma32(kf, qf[s], st[nb]);
      }
    }
    __builtin_amdgcn_s_setprio(0);

    // ---- row max via max3 tree (32 -> 11 -> 4 -> 1)
    float lv[11];
    #pragma unroll
    for (int i = 0; i < 10; i++){
      float e0 = (3*i   < 16) ? st[0][3*i  ] : st[1][3*i  -16];
      float e1 = (3*i+1 < 16) ? st[0][3*i+1] : st[1][3*i+1-16];
      float e2 = (3*i+2 < 16) ? st[0][3*i+2] : st[1][3*i+2-16];
      lv[i] = fmax3(e0, e1, e2);
    }
    lv[10] = fmaxf(st[1][14], st[1][15]);
    float q0 = fmax3(lv[0], lv[1], lv[2]);
    float q1 = fmax3(lv[3], lv[4], lv[5]);
    float q2 = fmax3(lv[6], lv[7], lv[8]);
    float q3 = fmaxf(lv[9], lv[10]);
    float mloc = fmax3(q0, q1, fmaxf(q2, q3));
    u32 ma = __builtin_bit_cast(u32, mloc), mb = ma;
    plane_swap(ma, mb);
    float mx = fmaxf(__builtin_bit_cast(float, ma), __builtin_bit_cast(float, mb));

    // ---- defer-max (T13): rescale only when some row grew past threshold
    if (__any(mx > m2 + 8.0f)){
      float mnew = fmaxf(m2, mx);
      float alpha = exp2f_fast(m2 - mnew);
      m2 = mnew;
      lsum *= alpha;
      #pragma unroll
      for (int nd = 0; nd < 2; nd++)
        #pragma unroll
        for (int i = 0; i < 16; i++) yacc[nd][i] *= alpha;
    }

    // ---- P = exp2(st - m2), bounded by 2^8
    #pragma unroll
    for (int nb = 0; nb < 2; nb++)
      #pragma unroll
      for (int i = 0; i < 16; i++)
        st[nb][i] = exp2f_fast(st[nb][i] - m2);

    // ---- pack P -> PV fragments (cvt_pk + permlane32_swap)
    bf16x8 pb[4];
    #pragma unroll
    for (int nb = 0; nb < 2; nb++){
      u32 c[8];
      #pragma unroll
      for (int i = 0; i < 8; i++) c[i] = cvtpk_bf16(st[nb][2 * i], st[nb][2 * i + 1]);
      plane_swap(c[0], c[2]); plane_swap(c[1], c[3]);
      plane_swap(c[4], c[6]); plane_swap(c[5], c[7]);
      u32 f0[4] = {c[0], c[1], c[2], c[3]};
      u32 f1[4] = {c[4], c[5], c[6], c[7]};
      pb[nb * 2 + 0] = *(bf16x8*)f0;
      pb[nb * 2 + 1] = *(bf16x8*)f1;
    }

    // ---- row sum on the matrix pipe: colsum(P) via ones-operand MFMA
    f32x16 sacc = {};
    // ---- PV (swapped), interleaved with the sum chain
    __builtin_amdgcn_s_setprio(1);
    #pragma unroll
    for (int ks = 0; ks < 4; ks++) sacc = mfma32(ones, pb[ks], sacc);
    #pragma unroll
    for (int nd = 0; nd < 2; nd++){
      const u16* vrow = Vsb + (nd * 32 + l31) * 64;
      #pragma unroll
      for (int ks = 0; ks < 4; ks++){
        bf16x8 vf = *(const bf16x8*)(vrow + (((ks * 2 + hi) ^ rx) << 3));
        yacc[nd] = mfma32(vf, pb[ks], yacc[nd]);
      }
    }
    __builtin_amdgcn_s_setprio(0);
    lsum += sacc[0];

    __builtin_amdgcn_sched_barrier(0);
    barrier_pin();
    cur ^= 1;
  }

  float inv = 1.0f / lsum;
  u16* op = opart + ((size_t)split * (Bb * Tt) + (size_t)b * Tt + qglob) * Cc + h * Dd;
  #pragma unroll
  for (int nd = 0; nd < 2; nd++){
    #pragma unroll
    for (int g = 0; g < 4; g++){
      ushort4 o;
      o.x = f2bf(yacc[nd][g * 4 + 0] * inv);
      o.y = f2bf(yacc[nd][g * 4 + 1] * inv);
      o.z = f2bf(yacc[nd][g * 4 + 2] * inv);
      o.w = f2bf(yacc[nd][g * 4 + 3] * inv);
      *(ushort4*)(op + nd * 32 + g * 8 + hi * 4) = o;
    }
  }
  if (hi == 0){
    float* mlp = ml + (((size_t)split * (Bb * Tt) + (size_t)b * Tt + qglob) * Hh + h) * 2;
    mlp[0] = m2; mlp[1] = lsum;
  }
}

// ---------------- combine 2 KV-splits (convex combination of normalized partials) ----
__global__ __launch_bounds__(256) void combine_kernel(const u16* __restrict__ opart,
    const float* __restrict__ ml, u16* __restrict__ y)
{
  int row = blockIdx.x;
  int d0  = threadIdx.x * 4;
  int h   = d0 >> 6;
  const float* p0 = ml + ((size_t)row * Hh + h) * 2;
  const float* p1 = ml + (((size_t)(Bb * Tt) + row) * Hh + h) * 2;
  float m0 = p0[0], l0 = p0[1], m1 = p1[0], l1 = p1[1];
  float M  = fmaxf(m0, m1);
  float u0 = l0 * exp2f_fast(m0 - M), u1 = l1 * exp2f_fast(m1 - M);
  float inv = 1.0f / (u0 + u1);
  float w0 = u0 * inv, w1 = u1 * inv;
  ushort4 a = *(const ushort4*)(opart + (size_t)row * Cc + d0);
  ushort4 c = *(const ushort4*)(opart + ((size_t)(Bb * Tt) + row) * Cc + d0);
  ushort4 o;
  o.x = f2bf(bf2f(a.x) * w0 + bf2f(c.x) * w1);
  o.y = f2bf(bf2f(a.y) * w0 + bf2f(c.y) * w1);
  o.z = f2bf(bf2f(a.z) * w0 + bf2f(c.z) * w1);
  o.w = f2bf(bf2f(a.w) * w0 + bf2f(c.w) * w1);
  *(ushort4*)(y + (size_t)row * Cc + d0) = o;
}

extern "C" void kernel_launch(void* const* d_in, const int* in_sizes, int n_in,
                              void* d_out, int out_size, void* d_ws, size_t ws_size,
                              hipStream_t stream)
{
  (void)in_sizes; (void)n_in; (void)out_size; (void)ws_size;
  const float* x    = (const float*)d_in[0];
  const float* Wq   = (const float*)d_in[1];
  const float* bq   = (const float*)d_in[2];
  const float* Wk   = (const float*)d_in[3];
  const float* bk   = (const float*)d_in[4];
  const float* Wv   = (const float*)d_in[5];
  const float* bv   = (const float*)d_in[6];
  const float* Wo   = (const float*)d_in[7];
  const float* bo   = (const float*)d_in[8];
  const float* ln1g = (const float*)d_in[9];
  const float* ln1b = (const float*)d_in[10];
  const float* ln2g = (const float*)d_in[11];
  const float* ln2b = (const float*)d_in[12];
  const float* W1   = (const float*)d_in[13];
  const float* b1   = (const float*)d_in[14];
  const float* W2   = (const float*)d_in[15];
  const float* b2   = (const float*)d_in[16];

  char* ws = (char*)d_ws;
  const size_t MB = 1024 * 1024;
  u16*   wqkvt = (u16*)(ws + 0 * MB);      // 6 MB  (Wq^T | Wk^T | Wv^T rows)
  u16*   wot   = (u16*)(ws + 6 * MB);      // 2 MB
  u16*   w1t   = (u16*)(ws + 8 * MB);      // 8 MB
  u16*   w2t   = (u16*)(ws + 16 * MB);     // 8 MB
  float* bqkv  = (float*)(ws + 24 * MB);   // 12 KB
  u16*   hbuf  = (u16*)(ws + 25 * MB);     // 8 MB  (h2 overlays after QKV gemm)
  u16*   qkv   = (u16*)(ws + 33 * MB);     // 24 MB (mb overlays 33..65 after attn)
  u16*   vtb   = (u16*)(ws + 57 * MB);     // 8 MB
  u16*   yb    = (u16*)(ws + 65 * MB);     // 8 MB
  u16*   opart = (u16*)(ws + 73 * MB);     // 16 MB (2 splits x 8 MB)
  float* x2    = (float*)(ws + 73 * MB);   // 16 MB (written by Wo gemm, after combine)
  float* mlb   = (float*)(ws + 89 * MB);   // 1 MB
  u16*   h2    = hbuf;
  u16*   mb    = qkv;

  dim3 tb(32, 8);
  transpose4_kernel<<<dim3(32, 32, 4), tb, 0, stream>>>(Wq, Wk, Wv, Wo,
      wqkvt, wqkvt + 1024 * 1024, wqkvt + 2048 * 1024, wot);
  transpose_cast_kernel<<<dim3(128, 32), tb, 0, stream>>>(W1, w1t, 1024, 4096);
  transpose_cast_kernel<<<dim3(32, 128), tb, 0, stream>>>(W2, w2t, 4096, 1024);
  pack3_kernel<<<12, 256, 0, stream>>>(bq, bk, bv, bqkv);

  ln_kernel<<<4096, 256, 0, stream>>>(x, ln1g, ln1b, hbuf);

  // fused QKV: 128x128 BK=32, 768 blocks, 4 blocks/CU (EPI 3: q cols pre-scaled)
  gemm32_kernel<3><<<dim3(32, 24), 256, 0, stream>>>(hbuf, wqkvt, bqkv, qkv, 1024, 1024, 3072);

  transpose_v_kernel<<<dim3(64, 2, 32), tb, 0, stream>>>(qkv + 2048, vtb);

  // KV-split x2 attention + combine
  attn_kernel<<<dim3(16, 32, 2), 256, 0, stream>>>(qkv, qkv + 1024, vtb, opart, mlb);
  combine_kernel<<<4096, 256, 0, stream>>>(opart, mlb, yb);

  // Wo: 64x64 tiles, 1024 blocks, 4 blocks/CU
  gemmc_kernel<64, 64, 4, 1><<<dim3(64, 16), 256, 0, stream>>>(yb, wot, bo, x, x2, 1024, 1024, 1024);

  ln_kernel<<<4096, 256, 0, stream>>>(x2, ln2g, ln2b, h2);

  // W1: 128x128 BK=32, 1024 blocks, 4 blocks/CU (gelu)
  gemm32_kernel<2><<<dim3(32, 32), 256, 0, stream>>>(h2, w1t, b1, mb, 1024, 1024, 4096);

  // W2: 64x64 tiles BK=64, 1024 blocks, 4 blocks/CU (R13 proven)
  gemmc_kernel<64, 64, 4, 1><<<dim3(64, 16), 256, 0, stream>>>(mb, w2t, b2, x2, (float*)d_out, 4096, 4096, 1024);
}